// Round 2
// baseline (1432.128 us; speedup 1.0000x reference)
//
#include <hip/hip_runtime.h>
#include <cstdint>

// SpikeModel: 3-layer stride-2 3x3 spiking CNN, T=20, bs=32.
// k1: conv1 fused over t (pot in regs), input staged in 8-t LDS chunks,
//     spikes -> bitpacked sp1 via shfl merge (no barrier).
// k2: conv2 fused over t; spike bits kept as u64 row words in LDS, taps
//     materialized by bfe+cvt in registers (no float expansion, no
//     expansion barriers); next-t bits prefetched into regs.
// k3: two-phase. k3a: conv3 sums for all (t,b) fully parallel (2560 blocks)
//     -> S3 fp32 in ws. k3b: elementwise membrane recurrence + t-inner
//     output write. Fallback to fused k3 if ws too small.
// fp32 accumulation order (ic asc, kh asc, kw asc per accumulator, bias
// added last) is IDENTICAL to round-1 (absmax 0.0) — do not reorder.

#define DECAY 0.2f
#define TH 0.5f

// -------------------------------------------------------------------------
// Kernel 1: conv1 (IC=2, 128x128 -> OC=32, 64x64), grid 32*64, block 256.
// -------------------------------------------------------------------------
__global__ __launch_bounds__(256, 4)
void k1_conv(const float* __restrict__ in, const float* __restrict__ w1,
             const float* __restrict__ b1, uint8_t* __restrict__ sp1)
{
    __shared__ float P[8 * 612];   // [tq][(ic*17+ihl)][18] cols 0..7=E, 8..16=O
    __shared__ float wl[576];      // [ic][kh][kw][oc]

    const int tid  = threadIdx.x;
    const int b    = blockIdx.x >> 6;
    const int tile = blockIdx.x & 63;
    const int oh0  = (tile >> 3) << 3;
    const int ow0  = (tile & 7) << 3;

    for (int idx = tid; idx < 576; idx += 256) {
        int oc = idx & 31, rest = idx >> 5;
        int ic = rest / 9, r9 = rest - ic * 9;
        wl[idx] = w1[(oc * 2 + ic) * 9 + r9];
    }

    const int oc0 = (tid >> 5) << 2;
    const int sl  = tid & 31;
    const int r   = sl >> 2;
    const int owp = sl & 3, owl = owp << 1;

    const float4 bias = *(const float4*)&b1[oc0];
    float pot[8];
    #pragma unroll
    for (int i = 0; i < 8; i++) pot[i] = 0.0f;

    for (int rb = 0; rb < 3; rb++) {
        const int t0 = rb * 8;
        const int nt = (rb == 2) ? 4 : 8;
        const int nq = nt >> 2;
        __syncthreads();               // P free (prev chunk reads done)
        for (int idx = tid; idx < 578 * nq; idx += 256) {
            int q   = (nq == 2) ? (idx & 1) : 0;
            int pix = (nq == 2) ? (idx >> 1) : idx;
            int c = pix / 289, rem = pix - c * 289;
            int ihl = rem / 17, iwl = rem - ihl * 17;
            int ih = 2 * oh0 - 1 + ihl;
            int iw = 2 * ow0 - 1 + iwl;
            float4 v = make_float4(0.f, 0.f, 0.f, 0.f);
            if (ih >= 0 && iw >= 0)
                v = *(const float4*)&in[(((size_t)(b * 2 + c) * 128 + ih) * 128 + iw) * 20 + t0 + q * 4];
            int col = (iwl & 1) ? ((iwl - 1) >> 1) : (8 + (iwl >> 1));
            float* dst = &P[(c * 17 + ihl) * 18 + col];
            int tq0 = q * 4;
            dst[(tq0 + 0) * 612] = v.x;
            dst[(tq0 + 1) * 612] = v.y;
            dst[(tq0 + 2) * 612] = v.z;
            dst[(tq0 + 3) * 612] = v.w;
        }
        __syncthreads();               // P(chunk) ready
        for (int tq = 0; tq < nt; tq++) {
            const int t = t0 + tq;
            float acc[8];
            #pragma unroll
            for (int i = 0; i < 8; i++) acc[i] = 0.0f;
            const float* Pt = &P[tq * 612];
            #pragma unroll
            for (int ic = 0; ic < 2; ic++) {
                #pragma unroll
                for (int kh = 0; kh < 3; kh++) {
                    const float* row = Pt + (ic * 17 + 2 * r + kh) * 18;
                    float2 eV = *(const float2*)&row[owl];       // eA,eB
                    float2 oV = *(const float2*)&row[8 + owl];   // oA,oB
                    float  oC = row[10 + owl];
                    const float* wb = &wl[(ic * 9 + kh * 3) * 32 + oc0];
                    float4 w0  = *(const float4*)(wb);
                    float4 w1v = *(const float4*)(wb + 32);
                    float4 w2v = *(const float4*)(wb + 64);
                    acc[0] += w0.x * oV.x;  acc[1] += w0.x * oV.y;
                    acc[2] += w0.y * oV.x;  acc[3] += w0.y * oV.y;
                    acc[4] += w0.z * oV.x;  acc[5] += w0.z * oV.y;
                    acc[6] += w0.w * oV.x;  acc[7] += w0.w * oV.y;
                    acc[0] += w1v.x * eV.x; acc[1] += w1v.x * eV.y;
                    acc[2] += w1v.y * eV.x; acc[3] += w1v.y * eV.y;
                    acc[4] += w1v.z * eV.x; acc[5] += w1v.z * eV.y;
                    acc[6] += w1v.w * eV.x; acc[7] += w1v.w * eV.y;
                    acc[0] += w2v.x * oV.y; acc[1] += w2v.x * oC;
                    acc[2] += w2v.y * oV.y; acc[3] += w2v.y * oC;
                    acc[4] += w2v.z * oV.y; acc[5] += w2v.z * oC;
                    acc[6] += w2v.w * oV.y; acc[7] += w2v.w * oC;
                }
            }
            uint32_t p = 0;
            #pragma unroll
            for (int k = 0; k < 4; k++) {
                float bk = ((const float*)&bias)[k];
                uint32_t v = 0;
                #pragma unroll
                for (int w = 0; w < 2; w++) {
                    float conv = acc[k * 2 + w] + bk;
                    float pp = pot[k * 2 + w];
                    float u = (pp > TH) ? conv : (pp * DECAY + conv);
                    pot[k * 2 + w] = u;
                    if (u > TH) v |= 1u << (owl + w);
                }
                p |= v << (8 * k);
            }
            p |= __shfl_xor((int)p, 1);
            p |= __shfl_xor((int)p, 2);
            if (owp == 0) {
                #pragma unroll
                for (int k = 0; k < 4; k++)
                    sp1[(((size_t)(t * 32 + b) * 32 + (oc0 + k)) * 64 + (oh0 + r)) * 8 + (ow0 >> 3)]
                        = (uint8_t)(p >> (8 * k));
            }
        }
    }
}

// -------------------------------------------------------------------------
// Kernel 2: conv2 (IC=32, 64x64 -> OC=32, 32x32), grid 32*16, block 256.
// Bits-in-LDS, taps via bfe+cvt, next-t prefetch, shfl byte merge.
// -------------------------------------------------------------------------
__global__ __launch_bounds__(256, 2)
void k2_conv(const uint8_t* __restrict__ sp1, const float* __restrict__ w2,
             const float* __restrict__ b2, uint8_t* __restrict__ sp2)
{
    __shared__ float wl[9216];                 // [ic][kh][kw][oc]
    __shared__ unsigned long long B[544];      // [ic][ihl] row bit-words

    const int tid  = threadIdx.x;
    const int b    = blockIdx.x >> 4;
    const int tile = blockIdx.x & 15;
    const int oh0  = (tile >> 2) << 3;
    const int ow0  = (tile & 3) << 3;

    for (int idx = tid; idx < 9216; idx += 256) {
        int oc = idx & 31, rest = idx >> 5;
        int ic = rest / 9, r9 = rest - ic * 9;
        wl[idx] = w2[(oc * 32 + ic) * 9 + r9];
    }

    const unsigned long long* sp1w = (const unsigned long long*)sp1;
    // per-thread staging words: tid, 256+tid, (tid<32: 512+tid)
    int w0i = tid, w1i = 256 + tid, w2i = 512 + tid;
    int ic0s = w0i / 17, ih0 = 2 * oh0 - 1 + (w0i - ic0s * 17);
    int ic1s = w1i / 17, ih1 = 2 * oh0 - 1 + (w1i - ic1s * 17);
    int ic2s = w2i / 17, ih2 = 2 * oh0 - 1 + (w2i - ic2s * 17);
    const size_t base0 = (size_t)(b * 32 + ic0s) * 64 + ih0;
    const size_t base1 = (size_t)(b * 32 + ic1s) * 64 + ih1;
    const size_t base2 = (size_t)(b * 32 + ic2s) * 64 + ih2;
    const bool v0ok = (ih0 >= 0), v1ok = (ih1 >= 0), v2ok = (tid < 32) && (ih2 >= 0);

    unsigned long long v0 = v0ok ? sp1w[base0] : 0ull;
    unsigned long long v1 = v1ok ? sp1w[base1] : 0ull;
    unsigned long long v2 = v2ok ? sp1w[base2] : 0ull;

    const int oc0 = (tid >> 5) << 2;
    const int sl  = tid & 31;
    const int r   = sl >> 2;
    const int owp = sl & 3, owl = owp << 1;
    const int sshift = 2 * (ow0 + owl) - 1;    // >= -1

    const float4 bias = *(const float4*)&b2[oc0];
    float pot[8];
    #pragma unroll
    for (int i = 0; i < 8; i++) pot[i] = 0.0f;

    for (int t = 0; t < 20; t++) {
        __syncthreads();               // B free from previous t's reads
        B[tid] = v0;
        B[256 + tid] = v1;
        if (tid < 32) B[512 + tid] = v2;
        __syncthreads();               // B(t) ready
        if (t < 19) {                  // prefetch t+1 (overlaps compute)
            size_t ts = (size_t)(t + 1) * 65536;
            v0 = v0ok ? sp1w[ts + base0] : 0ull;
            v1 = v1ok ? sp1w[ts + base1] : 0ull;
            v2 = v2ok ? sp1w[ts + base2] : 0ull;
        }

        float acc[8];
        #pragma unroll
        for (int i = 0; i < 8; i++) acc[i] = 0.0f;
        const unsigned long long* Bp = &B[2 * r];
        #pragma unroll 4
        for (int ic = 0; ic < 32; ic++) {
            #pragma unroll
            for (int kh = 0; kh < 3; kh++) {
                unsigned long long m = Bp[ic * 17 + kh];
                uint32_t bits = (sshift >= 0) ? (uint32_t)(m >> sshift)
                                              : (((uint32_t)m) << 1);
                float f0 = (float)(bits & 1u);
                float f1 = (float)((bits >> 1) & 1u);
                float f2 = (float)((bits >> 2) & 1u);
                float f3 = (float)((bits >> 3) & 1u);
                float f4 = (float)((bits >> 4) & 1u);
                const float* wb = &wl[(ic * 9 + kh * 3) * 32 + oc0];
                float4 wk0 = *(const float4*)(wb);
                float4 wk1 = *(const float4*)(wb + 32);
                float4 wk2 = *(const float4*)(wb + 64);
                acc[0] += wk0.x * f0;  acc[1] += wk0.x * f2;
                acc[2] += wk0.y * f0;  acc[3] += wk0.y * f2;
                acc[4] += wk0.z * f0;  acc[5] += wk0.z * f2;
                acc[6] += wk0.w * f0;  acc[7] += wk0.w * f2;
                acc[0] += wk1.x * f1;  acc[1] += wk1.x * f3;
                acc[2] += wk1.y * f1;  acc[3] += wk1.y * f3;
                acc[4] += wk1.z * f1;  acc[5] += wk1.z * f3;
                acc[6] += wk1.w * f1;  acc[7] += wk1.w * f3;
                acc[0] += wk2.x * f2;  acc[1] += wk2.x * f4;
                acc[2] += wk2.y * f2;  acc[3] += wk2.y * f4;
                acc[4] += wk2.z * f2;  acc[5] += wk2.z * f4;
                acc[6] += wk2.w * f2;  acc[7] += wk2.w * f4;
            }
        }

        uint32_t p = 0;
        #pragma unroll
        for (int k = 0; k < 4; k++) {
            float bk = ((const float*)&bias)[k];
            uint32_t v = 0;
            #pragma unroll
            for (int w = 0; w < 2; w++) {
                float conv = acc[k * 2 + w] + bk;
                float pp = pot[k * 2 + w];
                float u = (pp > TH) ? conv : (pp * DECAY + conv);
                pot[k * 2 + w] = u;
                if (u > TH) v |= 1u << (owl + w);
            }
            p |= v << (8 * k);
        }
        p |= __shfl_xor((int)p, 1);
        p |= __shfl_xor((int)p, 2);
        if (owp == 0) {
            #pragma unroll
            for (int k = 0; k < 4; k++)
                sp2[(((size_t)(t * 32 + b) * 32 + (oc0 + k)) * 32 + (oh0 + r)) * 4 + (ow0 >> 3)]
                    = (uint8_t)(p >> (8 * k));
        }
    }
}

// -------------------------------------------------------------------------
// Kernel 3 phase A: conv3 sums for one (t,b,oc-quarter), grid 20*32*4.
// -------------------------------------------------------------------------
__global__ __launch_bounds__(256, 4)
void k3a_conv(const uint8_t* __restrict__ sp2, const float* __restrict__ w3,
              float* __restrict__ S3)
{
    __shared__ float wl[2304];       // [ic][kh][kw][8oc]
    __shared__ uint32_t Bs[32 * 33]; // [ic][ih+1], slot 0 = zero pad

    const int bid = blockIdx.x;
    const int t   = bid >> 7;
    const int rem = bid & 127;
    const int b   = rem >> 2;
    const int q   = rem & 3;

    const int tid = threadIdx.x;
    const uint32_t* sp2w = (const uint32_t*)sp2;

    for (int idx = tid; idx < 2304; idx += 256) {
        int ocl = idx & 7, rest = idx >> 3;
        int ic = rest / 9, r9 = rest - ic * 9;
        wl[idx] = w3[((q * 8 + ocl) * 32 + ic) * 9 + r9];
    }
    for (int idx = tid; idx < 1056; idx += 256) {
        int ic = idx / 33, ihl = idx - ic * 33;
        int ih = ihl - 1;
        Bs[idx] = (ih >= 0) ? sp2w[((size_t)(t * 32 + b) * 32 + ic) * 32 + ih] : 0u;
    }
    __syncthreads();

    const int half = tid >> 7;
    const int oc0  = q * 8 + half * 4;
    const int r    = (tid >> 3) & 15;
    const int owp  = tid & 7;

    float acc[8];
    #pragma unroll
    for (int i = 0; i < 8; i++) acc[i] = 0.0f;

    const uint32_t* Brow = &Bs[2 * r];
    #pragma unroll 4
    for (int ic = 0; ic < 32; ic++) {
        #pragma unroll
        for (int kh = 0; kh < 3; kh++) {
            uint32_t m = Brow[ic * 33 + kh];   // row ih = 2r-1+kh (padded)
            unsigned long long rw = ((unsigned long long)m) << 1;
            uint32_t bits = (uint32_t)(rw >> (owp * 4));
            float f0 = (float)(bits & 1u);
            float f1 = (float)((bits >> 1) & 1u);
            float f2 = (float)((bits >> 2) & 1u);
            float f3 = (float)((bits >> 3) & 1u);
            float f4 = (float)((bits >> 4) & 1u);
            const float* wb = &wl[(ic * 9 + kh * 3) * 8 + half * 4];
            float4 wk0 = *(const float4*)(wb);
            float4 wk1 = *(const float4*)(wb + 8);
            float4 wk2 = *(const float4*)(wb + 16);
            acc[0] += wk0.x * f0;  acc[1] += wk0.x * f2;
            acc[2] += wk0.y * f0;  acc[3] += wk0.y * f2;
            acc[4] += wk0.z * f0;  acc[5] += wk0.z * f2;
            acc[6] += wk0.w * f0;  acc[7] += wk0.w * f2;
            acc[0] += wk1.x * f1;  acc[1] += wk1.x * f3;
            acc[2] += wk1.y * f1;  acc[3] += wk1.y * f3;
            acc[4] += wk1.z * f1;  acc[5] += wk1.z * f3;
            acc[6] += wk1.w * f1;  acc[7] += wk1.w * f3;
            acc[0] += wk2.x * f2;  acc[1] += wk2.x * f4;
            acc[2] += wk2.y * f2;  acc[3] += wk2.y * f4;
            acc[4] += wk2.z * f2;  acc[5] += wk2.z * f4;
            acc[6] += wk2.w * f2;  acc[7] += wk2.w * f4;
        }
    }
    #pragma unroll
    for (int k = 0; k < 4; k++) {
        float2 v = make_float2(acc[k * 2], acc[k * 2 + 1]);
        *(float2*)&S3[((size_t)(t * 32 + b) * 32 + (oc0 + k)) * 256 + r * 16 + 2 * owp] = v;
    }
}

// -------------------------------------------------------------------------
// Kernel 3 phase B: membrane recurrence + t-inner output, grid 32*32.
// Block = (b, oc); thread = pixel (r*16+ow).
// -------------------------------------------------------------------------
__global__ __launch_bounds__(256, 4)
void k3b_rec(const float* __restrict__ S3, const float* __restrict__ b3,
             float* __restrict__ out)
{
    const int b  = blockIdx.x >> 5;
    const int oc = blockIdx.x & 31;
    const int tid = threadIdx.x;
    const float bk = b3[oc];

    float p = 0.0f;
    uint32_t om = 0u;
    for (int t = 0; t < 20; t++) {
        float s = S3[((size_t)(t * 32 + b) * 32 + oc) * 256 + tid];
        float conv = s + bk;
        float u = (p > TH) ? conv : (p * DECAY + conv);
        p = u;
        if (u > TH) om |= 1u << t;
    }
    float* dst = &out[((size_t)b * 8192 + (oc << 8) + tid) * 20];
    #pragma unroll
    for (int qq = 0; qq < 5; qq++) {
        float4 v;
        v.x = ((om >> (qq * 4 + 0)) & 1u) ? 1.0f : 0.0f;
        v.y = ((om >> (qq * 4 + 1)) & 1u) ? 1.0f : 0.0f;
        v.z = ((om >> (qq * 4 + 2)) & 1u) ? 1.0f : 0.0f;
        v.w = ((om >> (qq * 4 + 3)) & 1u) ? 1.0f : 0.0f;
        *(float4*)&dst[qq * 4] = v;
    }
}

// -------------------------------------------------------------------------
// Fallback fused k3 (round-1 version) if ws is too small for S3.
// -------------------------------------------------------------------------
__global__ __launch_bounds__(256, 3)
void k3_fused(const uint8_t* __restrict__ sp2, const float* __restrict__ w3,
              const float* __restrict__ b3, float* __restrict__ out)
{
    __shared__ float wl[9216];
    __shared__ float P[8 * 9 * 18];

    const int tid  = threadIdx.x;
    const int b    = blockIdx.x >> 3;
    const int tile = blockIdx.x & 7;
    const int oh0  = (tile >> 1) << 2;
    const int ow0  = (tile & 1) << 3;

    for (int idx = tid; idx < 9216; idx += 256) {
        int oc = idx & 31, rest = idx >> 5;
        int ic = rest / 9, r9 = rest - ic * 9;
        wl[idx] = w3[(oc * 32 + ic) * 9 + r9];
    }

    const int ocg = tid >> 4, oc0 = ocg << 1;
    const int sl = tid & 15, r = sl >> 2, owp = sl & 3, owl = owp << 1;
    const float2 bias = *(const float2*)&b3[oc0];
    float pot[4];
    uint32_t om[4];
    #pragma unroll
    for (int i = 0; i < 4; i++) { pot[i] = 0.0f; om[i] = 0u; }

    for (int t = 0; t < 20; t++) {
        float acc[4];
        #pragma unroll
        for (int i = 0; i < 4; i++) acc[i] = 0.0f;
        for (int cc = 0; cc < 4; cc++) {
            __syncthreads();
            if (tid < 72) {
                int ic = tid / 9, ihl = tid - ic * 9;
                int ih = 2 * oh0 - 1 + ihl;
                uint32_t rowb = 0u;
                if (ih >= 0)
                    rowb = *(const uint32_t*)
                           &sp2[(((size_t)(t * 32 + b) * 32 + (cc * 8 + ic)) * 32 + ih) * 4];
                float* dst = &P[(ic * 9 + ihl) * 18];
                #pragma unroll
                for (int iwl = 0; iwl < 17; iwl++) {
                    int iw = 2 * ow0 - 1 + iwl;
                    int col = (iwl & 1) ? ((iwl - 1) >> 1) : (8 + (iwl >> 1));
                    dst[col] = (iw >= 0 && ((rowb >> iw) & 1u)) ? 1.0f : 0.0f;
                }
            }
            __syncthreads();
            #pragma unroll
            for (int ic = 0; ic < 8; ic++) {
                #pragma unroll
                for (int kh = 0; kh < 3; kh++) {
                    const float* row = &P[(ic * 9 + 2 * r + kh) * 18];
                    float eA = row[owl],     eB = row[owl + 1];
                    float oA = row[8 + owl], oB = row[9 + owl], oC = row[10 + owl];
                    const float* wb = &wl[((cc * 8 + ic) * 9 + kh * 3) * 32 + oc0];
                    float2 w0  = *(const float2*)(wb);
                    float2 w1v = *(const float2*)(wb + 32);
                    float2 w2v = *(const float2*)(wb + 64);
                    acc[0] += w0.x * oA;  acc[1] += w0.x * oB;
                    acc[2] += w0.y * oA;  acc[3] += w0.y * oB;
                    acc[0] += w1v.x * eA; acc[1] += w1v.x * eB;
                    acc[2] += w1v.y * eA; acc[3] += w1v.y * eB;
                    acc[0] += w2v.x * oB; acc[1] += w2v.x * oC;
                    acc[2] += w2v.y * oB; acc[3] += w2v.y * oC;
                }
            }
        }
        #pragma unroll
        for (int k = 0; k < 2; k++) {
            float bk = (k == 0) ? bias.x : bias.y;
            #pragma unroll
            for (int w = 0; w < 2; w++) {
                float conv = acc[k * 2 + w] + bk;
                float pp = pot[k * 2 + w];
                float u = (pp > TH) ? conv : (pp * DECAY + conv);
                pot[k * 2 + w] = u;
                if (u > TH) om[k * 2 + w] |= 1u << t;
            }
        }
    }

    #pragma unroll
    for (int k = 0; k < 2; k++) {
        #pragma unroll
        for (int w = 0; w < 2; w++) {
            int oc = oc0 + k;
            int oh = oh0 + r, ow = ow0 + owl + w;
            int i = (oc << 8) + (oh << 4) + ow;
            float* dst = &out[((size_t)b * 8192 + i) * 20];
            uint32_t m = om[k * 2 + w];
            #pragma unroll
            for (int qq = 0; qq < 5; qq++) {
                float4 v;
                v.x = ((m >> (qq * 4 + 0)) & 1u) ? 1.0f : 0.0f;
                v.y = ((m >> (qq * 4 + 1)) & 1u) ? 1.0f : 0.0f;
                v.z = ((m >> (qq * 4 + 2)) & 1u) ? 1.0f : 0.0f;
                v.w = ((m >> (qq * 4 + 3)) & 1u) ? 1.0f : 0.0f;
                *(float4*)&dst[qq * 4] = v;
            }
        }
    }
}

extern "C" void kernel_launch(void* const* d_in, const int* in_sizes, int n_in,
                              void* d_out, int out_size, void* d_ws, size_t ws_size,
                              hipStream_t stream)
{
    (void)in_sizes; (void)n_in; (void)out_size;
    const float* in = (const float*)d_in[0];
    const float* w1 = (const float*)d_in[1];
    const float* b1 = (const float*)d_in[2];
    const float* w2 = (const float*)d_in[3];
    const float* b2 = (const float*)d_in[4];
    const float* w3 = (const float*)d_in[5];
    const float* b3 = (const float*)d_in[6];

    const size_t SP1_BYTES = (size_t)20 * 32 * 32 * 64 * 8;   // 10,485,760
    const size_t SP2_BYTES = (size_t)20 * 32 * 32 * 32 * 4;   //  2,621,440
    const size_t S3_BYTES  = (size_t)20 * 32 * 32 * 256 * 4;  // 20,971,520

    uint8_t* base = (uint8_t*)d_ws;
    const bool twophase = ws_size >= S3_BYTES + SP2_BYTES;    // 23.6 MB

    uint8_t* sp1;
    uint8_t* sp2;
    float*   S3 = nullptr;
    if (twophase) {
        sp1 = base;                    // dead before k3a writes S3 over it
        S3  = (float*)base;
        sp2 = base + S3_BYTES;
    } else {
        sp1 = base;
        sp2 = base + SP1_BYTES;
    }

    k1_conv<<<32 * 64, 256, 0, stream>>>(in, w1, b1, sp1);
    k2_conv<<<32 * 16, 256, 0, stream>>>(sp1, w2, b2, sp2);
    if (twophase) {
        k3a_conv<<<20 * 32 * 4, 256, 0, stream>>>(sp2, w3, S3);
        k3b_rec<<<32 * 32, 256, 0, stream>>>(S3, b3, (float*)d_out);
    } else {
        k3_fused<<<32 * 8, 256, 0, stream>>>(sp2, w3, b3, (float*)d_out);
    }
}

// Round 3
// 590.466 us; speedup vs baseline: 2.4254x; 2.4254x over previous
//
#include <hip/hip_runtime.h>
#include <cstdint>

// SpikeModel: 3-layer stride-2 3x3 spiking CNN, T=20, bs=32.
// k1: full-width 1-row blocks; 3 input rows x 129 cols x 2 ic x ALL 20 t
//     staged once in LDS (coalesced 80B/pixel q-inner reads); thread =
//     (oc, 8-col octet) -> spike byte assembled in-thread; pot in regs.
// k2: conv2 fused over t; spike bits as u64 row words in LDS, taps via
//     bfe+cvt; next-t global prefetch; shfl byte merge. (unchanged, r2)
// k3: two-phase (k3a conv sums fully parallel -> S3; k3b elementwise
//     recurrence), fallback fused. (unchanged, r2)
// fp32 accumulation order per accumulator (ic asc, kh asc, kw asc, bias
// last) is IDENTICAL to rounds 1-2 (absmax 0.0) — do not reorder.

#define DECAY 0.2f
#define TH 0.5f

// -------------------------------------------------------------------------
// Kernel 1: conv1 (IC=2, 128x128 -> OC=32, 64x64), grid 32*64, block 256.
// Block = (b, out-row). LDS: P[t][ic*3+ihl][136]: E cols 0..63 at +0,
// O cols -1..127 (odd) at +68. Thread: oc = tid>>3, tw = tid&7.
// -------------------------------------------------------------------------
__global__ __launch_bounds__(256, 2)
void k1_conv(const float* __restrict__ in, const float* __restrict__ w1,
             const float* __restrict__ b1, uint8_t* __restrict__ sp1)
{
    __shared__ float P[20 * 816];   // 65,280 B

    const int tid = threadIdx.x;
    const int b   = blockIdx.x >> 6;
    const int row = blockIdx.x & 63;

    // stage 3 rows x 129 cols x 2 ic x 20 t, q-inner (80 B/pixel contiguous)
    for (int idx = tid; idx < 3870; idx += 256) {
        int q = idx % 5, px = idx / 5;
        int iwl = px % 129, rest = px / 129;
        int ihl = rest % 3, ic = rest / 3;
        int ih = 2 * row - 1 + ihl;          // in [-1, 127]
        int iw = iwl - 1;                    // in [-1, 127]
        float4 v = make_float4(0.f, 0.f, 0.f, 0.f);
        if (ih >= 0 && iw >= 0)
            v = *(const float4*)&in[(((size_t)(b * 2 + ic) * 128 + ih) * 128 + iw) * 20 + q * 4];
        // iwl odd -> even col -> E[(iwl-1)>>1]; iwl even -> odd col -> O[iwl>>1]
        int col = (iwl & 1) ? ((iwl - 1) >> 1) : (68 + (iwl >> 1));
        float* dst = &P[(ic * 3 + ihl) * 136 + col];
        int t0 = q * 4;
        dst[(t0 + 0) * 816] = v.x;
        dst[(t0 + 1) * 816] = v.y;
        dst[(t0 + 2) * 816] = v.z;
        dst[(t0 + 3) * 816] = v.w;
    }

    const int oc = tid >> 3;
    const int tw = tid & 7;

    float w[18];
    #pragma unroll
    for (int ic = 0; ic < 2; ic++)
        #pragma unroll
        for (int k9 = 0; k9 < 9; k9++)
            w[ic * 9 + k9] = w1[(oc * 2 + ic) * 9 + k9];
    const float bk = b1[oc];

    float pot[8];
    #pragma unroll
    for (int i = 0; i < 8; i++) pot[i] = 0.0f;

    __syncthreads();

    for (int t = 0; t < 20; t++) {
        float acc[8];
        #pragma unroll
        for (int i = 0; i < 8; i++) acc[i] = 0.0f;
        const float* Pt = &P[t * 816];
        #pragma unroll
        for (int ic = 0; ic < 2; ic++) {
            #pragma unroll
            for (int kh = 0; kh < 3; kh++) {
                const float* rowp = Pt + (ic * 3 + kh) * 136;
                float4 e0 = *(const float4*)&rowp[8 * tw];
                float4 e1 = *(const float4*)&rowp[8 * tw + 4];
                float4 o0 = *(const float4*)&rowp[68 + 8 * tw];
                float4 o1 = *(const float4*)&rowp[68 + 8 * tw + 4];
                float  o8 = rowp[68 + 8 * tw + 8];
                float wk0 = w[ic * 9 + kh * 3 + 0];
                float wk1 = w[ic * 9 + kh * 3 + 1];
                float wk2 = w[ic * 9 + kh * 3 + 2];
                // kw0: O[8tw+j], kw1: E[8tw+j], kw2: O[8tw+j+1]
                acc[0] += wk0 * o0.x; acc[1] += wk0 * o0.y;
                acc[2] += wk0 * o0.z; acc[3] += wk0 * o0.w;
                acc[4] += wk0 * o1.x; acc[5] += wk0 * o1.y;
                acc[6] += wk0 * o1.z; acc[7] += wk0 * o1.w;
                acc[0] += wk1 * e0.x; acc[1] += wk1 * e0.y;
                acc[2] += wk1 * e0.z; acc[3] += wk1 * e0.w;
                acc[4] += wk1 * e1.x; acc[5] += wk1 * e1.y;
                acc[6] += wk1 * e1.z; acc[7] += wk1 * e1.w;
                acc[0] += wk2 * o0.y; acc[1] += wk2 * o0.z;
                acc[2] += wk2 * o0.w; acc[3] += wk2 * o1.x;
                acc[4] += wk2 * o1.y; acc[5] += wk2 * o1.z;
                acc[6] += wk2 * o1.w; acc[7] += wk2 * o8;
            }
        }
        uint32_t v = 0;
        #pragma unroll
        for (int j = 0; j < 8; j++) {
            float conv = acc[j] + bk;
            float pp = pot[j];
            float u = (pp > TH) ? conv : (pp * DECAY + conv);
            pot[j] = u;
            if (u > TH) v |= 1u << j;
        }
        sp1[(((size_t)(t * 32 + b) * 32 + oc) * 64 + row) * 8 + tw] = (uint8_t)v;
    }
}

// -------------------------------------------------------------------------
// Kernel 2: conv2 (IC=32, 64x64 -> OC=32, 32x32), grid 32*16, block 256.
// Bits-in-LDS, taps via bfe+cvt, next-t prefetch, shfl byte merge.
// -------------------------------------------------------------------------
__global__ __launch_bounds__(256, 2)
void k2_conv(const uint8_t* __restrict__ sp1, const float* __restrict__ w2,
             const float* __restrict__ b2, uint8_t* __restrict__ sp2)
{
    __shared__ float wl[9216];                 // [ic][kh][kw][oc]
    __shared__ unsigned long long B[544];      // [ic][ihl] row bit-words

    const int tid  = threadIdx.x;
    const int b    = blockIdx.x >> 4;
    const int tile = blockIdx.x & 15;
    const int oh0  = (tile >> 2) << 3;
    const int ow0  = (tile & 3) << 3;

    for (int idx = tid; idx < 9216; idx += 256) {
        int oc = idx & 31, rest = idx >> 5;
        int ic = rest / 9, r9 = rest - ic * 9;
        wl[idx] = w2[(oc * 32 + ic) * 9 + r9];
    }

    const unsigned long long* sp1w = (const unsigned long long*)sp1;
    int w0i = tid, w1i = 256 + tid, w2i = 512 + tid;
    int ic0s = w0i / 17, ih0 = 2 * oh0 - 1 + (w0i - ic0s * 17);
    int ic1s = w1i / 17, ih1 = 2 * oh0 - 1 + (w1i - ic1s * 17);
    int ic2s = w2i / 17, ih2 = 2 * oh0 - 1 + (w2i - ic2s * 17);
    const size_t base0 = (size_t)(b * 32 + ic0s) * 64 + ih0;
    const size_t base1 = (size_t)(b * 32 + ic1s) * 64 + ih1;
    const size_t base2 = (size_t)(b * 32 + ic2s) * 64 + ih2;
    const bool v0ok = (ih0 >= 0), v1ok = (ih1 >= 0), v2ok = (tid < 32) && (ih2 >= 0);

    unsigned long long v0 = v0ok ? sp1w[base0] : 0ull;
    unsigned long long v1 = v1ok ? sp1w[base1] : 0ull;
    unsigned long long v2 = v2ok ? sp1w[base2] : 0ull;

    const int oc0 = (tid >> 5) << 2;
    const int sl  = tid & 31;
    const int r   = sl >> 2;
    const int owp = sl & 3, owl = owp << 1;
    const int sshift = 2 * (ow0 + owl) - 1;    // >= -1

    const float4 bias = *(const float4*)&b2[oc0];
    float pot[8];
    #pragma unroll
    for (int i = 0; i < 8; i++) pot[i] = 0.0f;

    for (int t = 0; t < 20; t++) {
        __syncthreads();               // B free from previous t's reads
        B[tid] = v0;
        B[256 + tid] = v1;
        if (tid < 32) B[512 + tid] = v2;
        __syncthreads();               // B(t) ready
        if (t < 19) {                  // prefetch t+1 (overlaps compute)
            size_t ts = (size_t)(t + 1) * 65536;
            v0 = v0ok ? sp1w[ts + base0] : 0ull;
            v1 = v1ok ? sp1w[ts + base1] : 0ull;
            v2 = v2ok ? sp1w[ts + base2] : 0ull;
        }

        float acc[8];
        #pragma unroll
        for (int i = 0; i < 8; i++) acc[i] = 0.0f;
        const unsigned long long* Bp = &B[2 * r];
        #pragma unroll 4
        for (int ic = 0; ic < 32; ic++) {
            #pragma unroll
            for (int kh = 0; kh < 3; kh++) {
                unsigned long long m = Bp[ic * 17 + kh];
                uint32_t bits = (sshift >= 0) ? (uint32_t)(m >> sshift)
                                              : (((uint32_t)m) << 1);
                float f0 = (float)(bits & 1u);
                float f1 = (float)((bits >> 1) & 1u);
                float f2 = (float)((bits >> 2) & 1u);
                float f3 = (float)((bits >> 3) & 1u);
                float f4 = (float)((bits >> 4) & 1u);
                const float* wb = &wl[(ic * 9 + kh * 3) * 32 + oc0];
                float4 wk0 = *(const float4*)(wb);
                float4 wk1 = *(const float4*)(wb + 32);
                float4 wk2 = *(const float4*)(wb + 64);
                acc[0] += wk0.x * f0;  acc[1] += wk0.x * f2;
                acc[2] += wk0.y * f0;  acc[3] += wk0.y * f2;
                acc[4] += wk0.z * f0;  acc[5] += wk0.z * f2;
                acc[6] += wk0.w * f0;  acc[7] += wk0.w * f2;
                acc[0] += wk1.x * f1;  acc[1] += wk1.x * f3;
                acc[2] += wk1.y * f1;  acc[3] += wk1.y * f3;
                acc[4] += wk1.z * f1;  acc[5] += wk1.z * f3;
                acc[6] += wk1.w * f1;  acc[7] += wk1.w * f3;
                acc[0] += wk2.x * f2;  acc[1] += wk2.x * f4;
                acc[2] += wk2.y * f2;  acc[3] += wk2.y * f4;
                acc[4] += wk2.z * f2;  acc[5] += wk2.z * f4;
                acc[6] += wk2.w * f2;  acc[7] += wk2.w * f4;
            }
        }

        uint32_t p = 0;
        #pragma unroll
        for (int k = 0; k < 4; k++) {
            float bkk = ((const float*)&bias)[k];
            uint32_t v = 0;
            #pragma unroll
            for (int w = 0; w < 2; w++) {
                float conv = acc[k * 2 + w] + bkk;
                float pp = pot[k * 2 + w];
                float u = (pp > TH) ? conv : (pp * DECAY + conv);
                pot[k * 2 + w] = u;
                if (u > TH) v |= 1u << (owl + w);
            }
            p |= v << (8 * k);
        }
        p |= __shfl_xor((int)p, 1);
        p |= __shfl_xor((int)p, 2);
        if (owp == 0) {
            #pragma unroll
            for (int k = 0; k < 4; k++)
                sp2[(((size_t)(t * 32 + b) * 32 + (oc0 + k)) * 32 + (oh0 + r)) * 4 + (ow0 >> 3)]
                    = (uint8_t)(p >> (8 * k));
        }
    }
}

// -------------------------------------------------------------------------
// Kernel 3 phase A: conv3 sums for one (t,b,oc-quarter), grid 20*32*4.
// -------------------------------------------------------------------------
__global__ __launch_bounds__(256, 4)
void k3a_conv(const uint8_t* __restrict__ sp2, const float* __restrict__ w3,
              float* __restrict__ S3)
{
    __shared__ float wl[2304];       // [ic][kh][kw][8oc]
    __shared__ uint32_t Bs[32 * 33]; // [ic][ih+1], slot 0 = zero pad

    const int bid = blockIdx.x;
    const int t   = bid >> 7;
    const int rem = bid & 127;
    const int b   = rem >> 2;
    const int q   = rem & 3;

    const int tid = threadIdx.x;
    const uint32_t* sp2w = (const uint32_t*)sp2;

    for (int idx = tid; idx < 2304; idx += 256) {
        int ocl = idx & 7, rest = idx >> 3;
        int ic = rest / 9, r9 = rest - ic * 9;
        wl[idx] = w3[((q * 8 + ocl) * 32 + ic) * 9 + r9];
    }
    for (int idx = tid; idx < 1056; idx += 256) {
        int ic = idx / 33, ihl = idx - ic * 33;
        int ih = ihl - 1;
        Bs[idx] = (ih >= 0) ? sp2w[((size_t)(t * 32 + b) * 32 + ic) * 32 + ih] : 0u;
    }
    __syncthreads();

    const int half = tid >> 7;
    const int oc0  = q * 8 + half * 4;
    const int r    = (tid >> 3) & 15;
    const int owp  = tid & 7;

    float acc[8];
    #pragma unroll
    for (int i = 0; i < 8; i++) acc[i] = 0.0f;

    const uint32_t* Brow = &Bs[2 * r];
    #pragma unroll 4
    for (int ic = 0; ic < 32; ic++) {
        #pragma unroll
        for (int kh = 0; kh < 3; kh++) {
            uint32_t m = Brow[ic * 33 + kh];   // row ih = 2r-1+kh (padded)
            unsigned long long rw = ((unsigned long long)m) << 1;
            uint32_t bits = (uint32_t)(rw >> (owp * 4));
            float f0 = (float)(bits & 1u);
            float f1 = (float)((bits >> 1) & 1u);
            float f2 = (float)((bits >> 2) & 1u);
            float f3 = (float)((bits >> 3) & 1u);
            float f4 = (float)((bits >> 4) & 1u);
            const float* wb = &wl[(ic * 9 + kh * 3) * 8 + half * 4];
            float4 wk0 = *(const float4*)(wb);
            float4 wk1 = *(const float4*)(wb + 8);
            float4 wk2 = *(const float4*)(wb + 16);
            acc[0] += wk0.x * f0;  acc[1] += wk0.x * f2;
            acc[2] += wk0.y * f0;  acc[3] += wk0.y * f2;
            acc[4] += wk0.z * f0;  acc[5] += wk0.z * f2;
            acc[6] += wk0.w * f0;  acc[7] += wk0.w * f2;
            acc[0] += wk1.x * f1;  acc[1] += wk1.x * f3;
            acc[2] += wk1.y * f1;  acc[3] += wk1.y * f3;
            acc[4] += wk1.z * f1;  acc[5] += wk1.z * f3;
            acc[6] += wk1.w * f1;  acc[7] += wk1.w * f3;
            acc[0] += wk2.x * f2;  acc[1] += wk2.x * f4;
            acc[2] += wk2.y * f2;  acc[3] += wk2.y * f4;
            acc[4] += wk2.z * f2;  acc[5] += wk2.z * f4;
            acc[6] += wk2.w * f2;  acc[7] += wk2.w * f4;
        }
    }
    #pragma unroll
    for (int k = 0; k < 4; k++) {
        float2 v = make_float2(acc[k * 2], acc[k * 2 + 1]);
        *(float2*)&S3[((size_t)(t * 32 + b) * 32 + (oc0 + k)) * 256 + r * 16 + 2 * owp] = v;
    }
}

// -------------------------------------------------------------------------
// Kernel 3 phase B: membrane recurrence + t-inner output, grid 32*32.
// -------------------------------------------------------------------------
__global__ __launch_bounds__(256, 4)
void k3b_rec(const float* __restrict__ S3, const float* __restrict__ b3,
             float* __restrict__ out)
{
    const int b  = blockIdx.x >> 5;
    const int oc = blockIdx.x & 31;
    const int tid = threadIdx.x;
    const float bk = b3[oc];

    float p = 0.0f;
    uint32_t om = 0u;
    for (int t = 0; t < 20; t++) {
        float s = S3[((size_t)(t * 32 + b) * 32 + oc) * 256 + tid];
        float conv = s + bk;
        float u = (p > TH) ? conv : (p * DECAY + conv);
        p = u;
        if (u > TH) om |= 1u << t;
    }
    float* dst = &out[((size_t)b * 8192 + (oc << 8) + tid) * 20];
    #pragma unroll
    for (int qq = 0; qq < 5; qq++) {
        float4 v;
        v.x = ((om >> (qq * 4 + 0)) & 1u) ? 1.0f : 0.0f;
        v.y = ((om >> (qq * 4 + 1)) & 1u) ? 1.0f : 0.0f;
        v.z = ((om >> (qq * 4 + 2)) & 1u) ? 1.0f : 0.0f;
        v.w = ((om >> (qq * 4 + 3)) & 1u) ? 1.0f : 0.0f;
        *(float4*)&dst[qq * 4] = v;
    }
}

// -------------------------------------------------------------------------
// Fallback fused k3 if ws is too small for S3.
// -------------------------------------------------------------------------
__global__ __launch_bounds__(256, 3)
void k3_fused(const uint8_t* __restrict__ sp2, const float* __restrict__ w3,
              const float* __restrict__ b3, float* __restrict__ out)
{
    __shared__ float wl[9216];
    __shared__ float P[8 * 9 * 18];

    const int tid  = threadIdx.x;
    const int b    = blockIdx.x >> 3;
    const int tile = blockIdx.x & 7;
    const int oh0  = (tile >> 1) << 2;
    const int ow0  = (tile & 1) << 3;

    for (int idx = tid; idx < 9216; idx += 256) {
        int oc = idx & 31, rest = idx >> 5;
        int ic = rest / 9, r9 = rest - ic * 9;
        wl[idx] = w3[(oc * 32 + ic) * 9 + r9];
    }

    const int ocg = tid >> 4, oc0 = ocg << 1;
    const int sl = tid & 15, r = sl >> 2, owp = sl & 3, owl = owp << 1;
    const float2 bias = *(const float2*)&b3[oc0];
    float pot[4];
    uint32_t om[4];
    #pragma unroll
    for (int i = 0; i < 4; i++) { pot[i] = 0.0f; om[i] = 0u; }

    for (int t = 0; t < 20; t++) {
        float acc[4];
        #pragma unroll
        for (int i = 0; i < 4; i++) acc[i] = 0.0f;
        for (int cc = 0; cc < 4; cc++) {
            __syncthreads();
            if (tid < 72) {
                int ic = tid / 9, ihl = tid - ic * 9;
                int ih = 2 * oh0 - 1 + ihl;
                uint32_t rowb = 0u;
                if (ih >= 0)
                    rowb = *(const uint32_t*)
                           &sp2[(((size_t)(t * 32 + b) * 32 + (cc * 8 + ic)) * 32 + ih) * 4];
                float* dst = &P[(ic * 9 + ihl) * 18];
                #pragma unroll
                for (int iwl = 0; iwl < 17; iwl++) {
                    int iw = 2 * ow0 - 1 + iwl;
                    int col = (iwl & 1) ? ((iwl - 1) >> 1) : (8 + (iwl >> 1));
                    dst[col] = (iw >= 0 && ((rowb >> iw) & 1u)) ? 1.0f : 0.0f;
                }
            }
            __syncthreads();
            #pragma unroll
            for (int ic = 0; ic < 8; ic++) {
                #pragma unroll
                for (int kh = 0; kh < 3; kh++) {
                    const float* row = &P[(ic * 9 + 2 * r + kh) * 18];
                    float eA = row[owl],     eB = row[owl + 1];
                    float oA = row[8 + owl], oB = row[9 + owl], oC = row[10 + owl];
                    const float* wb = &wl[((cc * 8 + ic) * 9 + kh * 3) * 32 + oc0];
                    float2 w0  = *(const float2*)(wb);
                    float2 w1v = *(const float2*)(wb + 32);
                    float2 w2v = *(const float2*)(wb + 64);
                    acc[0] += w0.x * oA;  acc[1] += w0.x * oB;
                    acc[2] += w0.y * oA;  acc[3] += w0.y * oB;
                    acc[0] += w1v.x * eA; acc[1] += w1v.x * eB;
                    acc[2] += w1v.y * eA; acc[3] += w1v.y * eB;
                    acc[0] += w2v.x * oB; acc[1] += w2v.x * oC;
                    acc[2] += w2v.y * oB; acc[3] += w2v.y * oC;
                }
            }
        }
        #pragma unroll
        for (int k = 0; k < 2; k++) {
            float bk = (k == 0) ? bias.x : bias.y;
            #pragma unroll
            for (int w = 0; w < 2; w++) {
                float conv = acc[k * 2 + w] + bk;
                float pp = pot[k * 2 + w];
                float u = (pp > TH) ? conv : (pp * DECAY + conv);
                pot[k * 2 + w] = u;
                if (u > TH) om[k * 2 + w] |= 1u << t;
            }
        }
    }

    #pragma unroll
    for (int k = 0; k < 2; k++) {
        #pragma unroll
        for (int w = 0; w < 2; w++) {
            int oc = oc0 + k;
            int oh = oh0 + r, ow = ow0 + owl + w;
            int i = (oc << 8) + (oh << 4) + ow;
            float* dst = &out[((size_t)b * 8192 + i) * 20];
            uint32_t m = om[k * 2 + w];
            #pragma unroll
            for (int qq = 0; qq < 5; qq++) {
                float4 v;
                v.x = ((m >> (qq * 4 + 0)) & 1u) ? 1.0f : 0.0f;
                v.y = ((m >> (qq * 4 + 1)) & 1u) ? 1.0f : 0.0f;
                v.z = ((m >> (qq * 4 + 2)) & 1u) ? 1.0f : 0.0f;
                v.w = ((m >> (qq * 4 + 3)) & 1u) ? 1.0f : 0.0f;
                *(float4*)&dst[qq * 4] = v;
            }
        }
    }
}

extern "C" void kernel_launch(void* const* d_in, const int* in_sizes, int n_in,
                              void* d_out, int out_size, void* d_ws, size_t ws_size,
                              hipStream_t stream)
{
    (void)in_sizes; (void)n_in; (void)out_size;
    const float* in = (const float*)d_in[0];
    const float* w1 = (const float*)d_in[1];
    const float* b1 = (const float*)d_in[2];
    const float* w2 = (const float*)d_in[3];
    const float* b2 = (const float*)d_in[4];
    const float* w3 = (const float*)d_in[5];
    const float* b3 = (const float*)d_in[6];

    const size_t SP1_BYTES = (size_t)20 * 32 * 32 * 64 * 8;   // 10,485,760
    const size_t SP2_BYTES = (size_t)20 * 32 * 32 * 32 * 4;   //  2,621,440
    const size_t S3_BYTES  = (size_t)20 * 32 * 32 * 256 * 4;  // 20,971,520

    uint8_t* base = (uint8_t*)d_ws;
    const bool twophase = ws_size >= S3_BYTES + SP2_BYTES;    // 23.6 MB

    uint8_t* sp1;
    uint8_t* sp2;
    float*   S3 = nullptr;
    if (twophase) {
        sp1 = base;                    // dead before k3a writes S3 over it
        S3  = (float*)base;
        sp2 = base + S3_BYTES;
    } else {
        sp1 = base;
        sp2 = base + SP1_BYTES;
    }

    k1_conv<<<32 * 64, 256, 0, stream>>>(in, w1, b1, sp1);
    k2_conv<<<32 * 16, 256, 0, stream>>>(sp1, w2, b2, sp2);
    if (twophase) {
        k3a_conv<<<20 * 32 * 4, 256, 0, stream>>>(sp2, w3, S3);
        k3b_rec<<<32 * 32, 256, 0, stream>>>(S3, b3, (float*)d_out);
    } else {
        k3_fused<<<32 * 8, 256, 0, stream>>>(sp2, w3, b3, (float*)d_out);
    }
}

// Round 4
// 577.100 us; speedup vs baseline: 2.4816x; 1.0232x over previous
//
#include <hip/hip_runtime.h>
#include <cstdint>

// SpikeModel: 3-layer stride-2 3x3 spiking CNN, T=20, bs=32.
// k1:  conv1 fused over t (pot in regs), full-width 1-row blocks. (r3)
// k2a: conv2 SUMS only, fully parallel over (t,b,tile) -> S2 fp32 in ws.
//      Thread = 4oc x 4ow (16 acc), bits as u64 rows in LDS, taps via
//      bfe+cvt. grid 5120 blocks (vs 512 fused) -> occupancy 3x.
// k2b: elementwise membrane recurrence over t, ballot -> sp2 bits.
// k3:  two-phase (k3a conv sums -> S3; k3b recurrence). (r2)
// Fallbacks when ws is small: fused k2_conv (r3) / fused k3 (r1).
// fp32 accumulation order per accumulator (ic asc, kh asc, kw asc, bias
// last) and the recurrence expression text are IDENTICAL to rounds 1-3
// (absmax 0.0 three times) — do not reorder or re-associate.

#define DECAY 0.2f
#define TH 0.5f

// -------------------------------------------------------------------------
// Kernel 1: conv1 (IC=2, 128x128 -> OC=32, 64x64), grid 32*64, block 256.
// Block = (b, out-row). P[t][ic*3+ihl][136]: E cols at +0, O cols at +68.
// -------------------------------------------------------------------------
__global__ __launch_bounds__(256, 2)
void k1_conv(const float* __restrict__ in, const float* __restrict__ w1,
             const float* __restrict__ b1, uint8_t* __restrict__ sp1)
{
    __shared__ float P[20 * 816];   // 65,280 B

    const int tid = threadIdx.x;
    const int b   = blockIdx.x >> 6;
    const int row = blockIdx.x & 63;

    for (int idx = tid; idx < 3870; idx += 256) {
        int q = idx % 5, px = idx / 5;
        int iwl = px % 129, rest = px / 129;
        int ihl = rest % 3, ic = rest / 3;
        int ih = 2 * row - 1 + ihl;
        int iw = iwl - 1;
        float4 v = make_float4(0.f, 0.f, 0.f, 0.f);
        if (ih >= 0 && iw >= 0)
            v = *(const float4*)&in[(((size_t)(b * 2 + ic) * 128 + ih) * 128 + iw) * 20 + q * 4];
        int col = (iwl & 1) ? ((iwl - 1) >> 1) : (68 + (iwl >> 1));
        float* dst = &P[(ic * 3 + ihl) * 136 + col];
        int t0 = q * 4;
        dst[(t0 + 0) * 816] = v.x;
        dst[(t0 + 1) * 816] = v.y;
        dst[(t0 + 2) * 816] = v.z;
        dst[(t0 + 3) * 816] = v.w;
    }

    const int oc = tid >> 3;
    const int tw = tid & 7;

    float w[18];
    #pragma unroll
    for (int ic = 0; ic < 2; ic++)
        #pragma unroll
        for (int k9 = 0; k9 < 9; k9++)
            w[ic * 9 + k9] = w1[(oc * 2 + ic) * 9 + k9];
    const float bk = b1[oc];

    float pot[8];
    #pragma unroll
    for (int i = 0; i < 8; i++) pot[i] = 0.0f;

    __syncthreads();

    for (int t = 0; t < 20; t++) {
        float acc[8];
        #pragma unroll
        for (int i = 0; i < 8; i++) acc[i] = 0.0f;
        const float* Pt = &P[t * 816];
        #pragma unroll
        for (int ic = 0; ic < 2; ic++) {
            #pragma unroll
            for (int kh = 0; kh < 3; kh++) {
                const float* rowp = Pt + (ic * 3 + kh) * 136;
                float4 e0 = *(const float4*)&rowp[8 * tw];
                float4 e1 = *(const float4*)&rowp[8 * tw + 4];
                float4 o0 = *(const float4*)&rowp[68 + 8 * tw];
                float4 o1 = *(const float4*)&rowp[68 + 8 * tw + 4];
                float  o8 = rowp[68 + 8 * tw + 8];
                float wk0 = w[ic * 9 + kh * 3 + 0];
                float wk1 = w[ic * 9 + kh * 3 + 1];
                float wk2 = w[ic * 9 + kh * 3 + 2];
                acc[0] += wk0 * o0.x; acc[1] += wk0 * o0.y;
                acc[2] += wk0 * o0.z; acc[3] += wk0 * o0.w;
                acc[4] += wk0 * o1.x; acc[5] += wk0 * o1.y;
                acc[6] += wk0 * o1.z; acc[7] += wk0 * o1.w;
                acc[0] += wk1 * e0.x; acc[1] += wk1 * e0.y;
                acc[2] += wk1 * e0.z; acc[3] += wk1 * e0.w;
                acc[4] += wk1 * e1.x; acc[5] += wk1 * e1.y;
                acc[6] += wk1 * e1.z; acc[7] += wk1 * e1.w;
                acc[0] += wk2 * o0.y; acc[1] += wk2 * o0.z;
                acc[2] += wk2 * o0.w; acc[3] += wk2 * o1.x;
                acc[4] += wk2 * o1.y; acc[5] += wk2 * o1.z;
                acc[6] += wk2 * o1.w; acc[7] += wk2 * o8;
            }
        }
        uint32_t v = 0;
        #pragma unroll
        for (int j = 0; j < 8; j++) {
            float conv = acc[j] + bk;
            float pp = pot[j];
            float u = (pp > TH) ? conv : (pp * DECAY + conv);
            pot[j] = u;
            if (u > TH) v |= 1u << j;
        }
        sp1[(((size_t)(t * 32 + b) * 32 + oc) * 64 + row) * 8 + tw] = (uint8_t)v;
    }
}

// -------------------------------------------------------------------------
// Kernel 2a: conv2 sums (IC=32, 64x64 -> OC=32, 32x32), no recurrence.
// grid 20*32*8 (t,b, 4 oh-bands x 2 ow-halves), block 256.
// Thread = 4oc x 4ow: ocg=tid>>5, r=(tid>>2)&7, owq=tid&3.
// -------------------------------------------------------------------------
__global__ __launch_bounds__(256, 3)
void k2a_conv(const uint8_t* __restrict__ sp1, const float* __restrict__ w2,
              float* __restrict__ S2)
{
    __shared__ float wl[9216];                 // [ic][kh][kw][oc]
    __shared__ unsigned long long B[544];      // [ic][ihl] row bit-words

    const int tid  = threadIdx.x;
    const int bid  = blockIdx.x;
    const int t    = bid >> 8;
    const int rem  = bid & 255;
    const int b    = rem >> 3;
    const int tile = rem & 7;
    const int oh0  = (tile >> 1) << 3;     // 0,8,16,24
    const int ow0  = (tile & 1) << 4;      // 0,16

    for (int idx = tid; idx < 9216; idx += 256) {
        int oc = idx & 31, rest = idx >> 5;
        int ic = rest / 9, r9 = rest - ic * 9;
        wl[idx] = w2[(oc * 32 + ic) * 9 + r9];
    }
    const unsigned long long* sp1w = (const unsigned long long*)sp1;
    for (int idx = tid; idx < 544; idx += 256) {
        int ic = idx / 17, ihl = idx - ic * 17;
        int ih = 2 * oh0 - 1 + ihl;
        B[idx] = (ih >= 0) ? sp1w[((size_t)(t * 32 + b) * 32 + ic) * 64 + ih] : 0ull;
    }
    __syncthreads();

    const int oc0 = (tid >> 5) << 2;
    const int r   = (tid >> 2) & 7;
    const int owl = (tid & 3) << 2;
    const int sshift = 2 * (ow0 + owl) - 1;    // >= -1

    float acc[4][4];
    #pragma unroll
    for (int k = 0; k < 4; k++)
        #pragma unroll
        for (int j = 0; j < 4; j++) acc[k][j] = 0.0f;

    #pragma unroll 4
    for (int ic = 0; ic < 32; ic++) {
        #pragma unroll
        for (int kh = 0; kh < 3; kh++) {
            unsigned long long m = B[ic * 17 + 2 * r + kh];
            uint32_t bits = (sshift >= 0) ? (uint32_t)(m >> sshift)
                                          : (((uint32_t)m) << 1);
            float f[9];
            #pragma unroll
            for (int i = 0; i < 9; i++) f[i] = (float)((bits >> i) & 1u);
            const float* wb = &wl[(ic * 9 + kh * 3) * 32 + oc0];
            float4 wk0 = *(const float4*)(wb);
            float4 wk1 = *(const float4*)(wb + 32);
            float4 wk2 = *(const float4*)(wb + 64);
            #pragma unroll
            for (int k = 0; k < 4; k++) {
                float w0 = ((const float*)&wk0)[k];
                float w1v = ((const float*)&wk1)[k];
                float w2v = ((const float*)&wk2)[k];
                #pragma unroll
                for (int j = 0; j < 4; j++) {
                    acc[k][j] += w0 * f[j];        // kw=0
                    acc[k][j] += w1v * f[j + 1];   // kw=1
                    acc[k][j] += w2v * f[j + 2];   // kw=2
                }
            }
        }
    }

    #pragma unroll
    for (int k = 0; k < 4; k++) {
        float4 v = make_float4(acc[k][0], acc[k][1], acc[k][2], acc[k][3]);
        *(float4*)&S2[((size_t)(t * 32 + b) * 32 + (oc0 + k)) * 1024
                      + (oh0 + r) * 32 + ow0 + owl] = v;
    }
}

// -------------------------------------------------------------------------
// Kernel 2b: membrane recurrence for layer 2, grid 32*32*4, block 256.
// Thread = one pixel; spike bits gathered per-wave via ballot.
// -------------------------------------------------------------------------
__global__ __launch_bounds__(256, 4)
void k2b_rec(const float* __restrict__ S2, const float* __restrict__ b2,
             uint8_t* __restrict__ sp2)
{
    const int bid = blockIdx.x;
    const int b   = bid >> 7;
    const int rem = bid & 127;
    const int oc  = rem >> 2;
    const int q   = rem & 3;
    const int tid = threadIdx.x;
    const int px  = q * 256 + tid;
    const float bk = b2[oc];
    uint32_t* sp2w = (uint32_t*)sp2;

    float sv[20];
    #pragma unroll
    for (int t = 0; t < 20; t++)
        sv[t] = S2[((size_t)(t * 32 + b) * 32 + oc) * 1024 + px];

    const int lane = tid & 63;
    float p = 0.0f;
    #pragma unroll
    for (int t = 0; t < 20; t++) {
        float conv = sv[t] + bk;
        float u = (p > TH) ? conv : (p * DECAY + conv);
        p = u;
        unsigned long long mk = __ballot(u > TH);
        if (lane == 0)
            sp2w[((size_t)(t * 32 + b) * 32 + oc) * 32 + (px >> 5)] = (uint32_t)mk;
        if (lane == 32)
            sp2w[((size_t)(t * 32 + b) * 32 + oc) * 32 + (px >> 5)] = (uint32_t)(mk >> 32);
    }
}

// -------------------------------------------------------------------------
// Kernel 2 (FALLBACK, fused over t): round-3 version.
// -------------------------------------------------------------------------
__global__ __launch_bounds__(256, 2)
void k2_conv(const uint8_t* __restrict__ sp1, const float* __restrict__ w2,
             const float* __restrict__ b2, uint8_t* __restrict__ sp2)
{
    __shared__ float wl[9216];
    __shared__ unsigned long long B[544];

    const int tid  = threadIdx.x;
    const int b    = blockIdx.x >> 4;
    const int tile = blockIdx.x & 15;
    const int oh0  = (tile >> 2) << 3;
    const int ow0  = (tile & 3) << 3;

    for (int idx = tid; idx < 9216; idx += 256) {
        int oc = idx & 31, rest = idx >> 5;
        int ic = rest / 9, r9 = rest - ic * 9;
        wl[idx] = w2[(oc * 32 + ic) * 9 + r9];
    }

    const unsigned long long* sp1w = (const unsigned long long*)sp1;
    int w0i = tid, w1i = 256 + tid, w2i = 512 + tid;
    int ic0s = w0i / 17, ih0 = 2 * oh0 - 1 + (w0i - ic0s * 17);
    int ic1s = w1i / 17, ih1 = 2 * oh0 - 1 + (w1i - ic1s * 17);
    int ic2s = w2i / 17, ih2 = 2 * oh0 - 1 + (w2i - ic2s * 17);
    const size_t base0 = (size_t)(b * 32 + ic0s) * 64 + ih0;
    const size_t base1 = (size_t)(b * 32 + ic1s) * 64 + ih1;
    const size_t base2 = (size_t)(b * 32 + ic2s) * 64 + ih2;
    const bool v0ok = (ih0 >= 0), v1ok = (ih1 >= 0), v2ok = (tid < 32) && (ih2 >= 0);

    unsigned long long v0 = v0ok ? sp1w[base0] : 0ull;
    unsigned long long v1 = v1ok ? sp1w[base1] : 0ull;
    unsigned long long v2 = v2ok ? sp1w[base2] : 0ull;

    const int oc0 = (tid >> 5) << 2;
    const int sl  = tid & 31;
    const int r   = sl >> 2;
    const int owp = sl & 3, owl = owp << 1;
    const int sshift = 2 * (ow0 + owl) - 1;

    const float4 bias = *(const float4*)&b2[oc0];
    float pot[8];
    #pragma unroll
    for (int i = 0; i < 8; i++) pot[i] = 0.0f;

    for (int t = 0; t < 20; t++) {
        __syncthreads();
        B[tid] = v0;
        B[256 + tid] = v1;
        if (tid < 32) B[512 + tid] = v2;
        __syncthreads();
        if (t < 19) {
            size_t ts = (size_t)(t + 1) * 65536;
            v0 = v0ok ? sp1w[ts + base0] : 0ull;
            v1 = v1ok ? sp1w[ts + base1] : 0ull;
            v2 = v2ok ? sp1w[ts + base2] : 0ull;
        }

        float acc[8];
        #pragma unroll
        for (int i = 0; i < 8; i++) acc[i] = 0.0f;
        const unsigned long long* Bp = &B[2 * r];
        #pragma unroll 4
        for (int ic = 0; ic < 32; ic++) {
            #pragma unroll
            for (int kh = 0; kh < 3; kh++) {
                unsigned long long m = Bp[ic * 17 + kh];
                uint32_t bits = (sshift >= 0) ? (uint32_t)(m >> sshift)
                                              : (((uint32_t)m) << 1);
                float f0 = (float)(bits & 1u);
                float f1 = (float)((bits >> 1) & 1u);
                float f2 = (float)((bits >> 2) & 1u);
                float f3 = (float)((bits >> 3) & 1u);
                float f4 = (float)((bits >> 4) & 1u);
                const float* wb = &wl[(ic * 9 + kh * 3) * 32 + oc0];
                float4 wk0 = *(const float4*)(wb);
                float4 wk1 = *(const float4*)(wb + 32);
                float4 wk2 = *(const float4*)(wb + 64);
                acc[0] += wk0.x * f0;  acc[1] += wk0.x * f2;
                acc[2] += wk0.y * f0;  acc[3] += wk0.y * f2;
                acc[4] += wk0.z * f0;  acc[5] += wk0.z * f2;
                acc[6] += wk0.w * f0;  acc[7] += wk0.w * f2;
                acc[0] += wk1.x * f1;  acc[1] += wk1.x * f3;
                acc[2] += wk1.y * f1;  acc[3] += wk1.y * f3;
                acc[4] += wk1.z * f1;  acc[5] += wk1.z * f3;
                acc[6] += wk1.w * f1;  acc[7] += wk1.w * f3;
                acc[0] += wk2.x * f2;  acc[1] += wk2.x * f4;
                acc[2] += wk2.y * f2;  acc[3] += wk2.y * f4;
                acc[4] += wk2.z * f2;  acc[5] += wk2.z * f4;
                acc[6] += wk2.w * f2;  acc[7] += wk2.w * f4;
            }
        }

        uint32_t p = 0;
        #pragma unroll
        for (int k = 0; k < 4; k++) {
            float bkk = ((const float*)&bias)[k];
            uint32_t v = 0;
            #pragma unroll
            for (int w = 0; w < 2; w++) {
                float conv = acc[k * 2 + w] + bkk;
                float pp = pot[k * 2 + w];
                float u = (pp > TH) ? conv : (pp * DECAY + conv);
                pot[k * 2 + w] = u;
                if (u > TH) v |= 1u << (owl + w);
            }
            p |= v << (8 * k);
        }
        p |= __shfl_xor((int)p, 1);
        p |= __shfl_xor((int)p, 2);
        if (owp == 0) {
            #pragma unroll
            for (int k = 0; k < 4; k++)
                sp2[(((size_t)(t * 32 + b) * 32 + (oc0 + k)) * 32 + (oh0 + r)) * 4 + (ow0 >> 3)]
                    = (uint8_t)(p >> (8 * k));
        }
    }
}

// -------------------------------------------------------------------------
// Kernel 3 phase A: conv3 sums for one (t,b,oc-quarter), grid 20*32*4.
// -------------------------------------------------------------------------
__global__ __launch_bounds__(256, 4)
void k3a_conv(const uint8_t* __restrict__ sp2, const float* __restrict__ w3,
              float* __restrict__ S3)
{
    __shared__ float wl[2304];
    __shared__ uint32_t Bs[32 * 33];

    const int bid = blockIdx.x;
    const int t   = bid >> 7;
    const int rem = bid & 127;
    const int b   = rem >> 2;
    const int q   = rem & 3;

    const int tid = threadIdx.x;
    const uint32_t* sp2w = (const uint32_t*)sp2;

    for (int idx = tid; idx < 2304; idx += 256) {
        int ocl = idx & 7, rest = idx >> 3;
        int ic = rest / 9, r9 = rest - ic * 9;
        wl[idx] = w3[((q * 8 + ocl) * 32 + ic) * 9 + r9];
    }
    for (int idx = tid; idx < 1056; idx += 256) {
        int ic = idx / 33, ihl = idx - ic * 33;
        int ih = ihl - 1;
        Bs[idx] = (ih >= 0) ? sp2w[((size_t)(t * 32 + b) * 32 + ic) * 32 + ih] : 0u;
    }
    __syncthreads();

    const int half = tid >> 7;
    const int oc0  = q * 8 + half * 4;
    const int r    = (tid >> 3) & 15;
    const int owp  = tid & 7;

    float acc[8];
    #pragma unroll
    for (int i = 0; i < 8; i++) acc[i] = 0.0f;

    const uint32_t* Brow = &Bs[2 * r];
    #pragma unroll 4
    for (int ic = 0; ic < 32; ic++) {
        #pragma unroll
        for (int kh = 0; kh < 3; kh++) {
            uint32_t m = Brow[ic * 33 + kh];
            unsigned long long rw = ((unsigned long long)m) << 1;
            uint32_t bits = (uint32_t)(rw >> (owp * 4));
            float f0 = (float)(bits & 1u);
            float f1 = (float)((bits >> 1) & 1u);
            float f2 = (float)((bits >> 2) & 1u);
            float f3 = (float)((bits >> 3) & 1u);
            float f4 = (float)((bits >> 4) & 1u);
            const float* wb = &wl[(ic * 9 + kh * 3) * 8 + half * 4];
            float4 wk0 = *(const float4*)(wb);
            float4 wk1 = *(const float4*)(wb + 8);
            float4 wk2 = *(const float4*)(wb + 16);
            acc[0] += wk0.x * f0;  acc[1] += wk0.x * f2;
            acc[2] += wk0.y * f0;  acc[3] += wk0.y * f2;
            acc[4] += wk0.z * f0;  acc[5] += wk0.z * f2;
            acc[6] += wk0.w * f0;  acc[7] += wk0.w * f2;
            acc[0] += wk1.x * f1;  acc[1] += wk1.x * f3;
            acc[2] += wk1.y * f1;  acc[3] += wk1.y * f3;
            acc[4] += wk1.z * f1;  acc[5] += wk1.z * f3;
            acc[6] += wk1.w * f1;  acc[7] += wk1.w * f3;
            acc[0] += wk2.x * f2;  acc[1] += wk2.x * f4;
            acc[2] += wk2.y * f2;  acc[3] += wk2.y * f4;
            acc[4] += wk2.z * f2;  acc[5] += wk2.z * f4;
            acc[6] += wk2.w * f2;  acc[7] += wk2.w * f4;
        }
    }
    #pragma unroll
    for (int k = 0; k < 4; k++) {
        float2 v = make_float2(acc[k * 2], acc[k * 2 + 1]);
        *(float2*)&S3[((size_t)(t * 32 + b) * 32 + (oc0 + k)) * 256 + r * 16 + 2 * owp] = v;
    }
}

// -------------------------------------------------------------------------
// Kernel 3 phase B: membrane recurrence + t-inner output, grid 32*32.
// -------------------------------------------------------------------------
__global__ __launch_bounds__(256, 4)
void k3b_rec(const float* __restrict__ S3, const float* __restrict__ b3,
             float* __restrict__ out)
{
    const int b  = blockIdx.x >> 5;
    const int oc = blockIdx.x & 31;
    const int tid = threadIdx.x;
    const float bk = b3[oc];

    float p = 0.0f;
    uint32_t om = 0u;
    for (int t = 0; t < 20; t++) {
        float s = S3[((size_t)(t * 32 + b) * 32 + oc) * 256 + tid];
        float conv = s + bk;
        float u = (p > TH) ? conv : (p * DECAY + conv);
        p = u;
        if (u > TH) om |= 1u << t;
    }
    float* dst = &out[((size_t)b * 8192 + (oc << 8) + tid) * 20];
    #pragma unroll
    for (int qq = 0; qq < 5; qq++) {
        float4 v;
        v.x = ((om >> (qq * 4 + 0)) & 1u) ? 1.0f : 0.0f;
        v.y = ((om >> (qq * 4 + 1)) & 1u) ? 1.0f : 0.0f;
        v.z = ((om >> (qq * 4 + 2)) & 1u) ? 1.0f : 0.0f;
        v.w = ((om >> (qq * 4 + 3)) & 1u) ? 1.0f : 0.0f;
        *(float4*)&dst[qq * 4] = v;
    }
}

// -------------------------------------------------------------------------
// Fallback fused k3 if ws is too small for S3.
// -------------------------------------------------------------------------
__global__ __launch_bounds__(256, 3)
void k3_fused(const uint8_t* __restrict__ sp2, const float* __restrict__ w3,
              const float* __restrict__ b3, float* __restrict__ out)
{
    __shared__ float wl[9216];
    __shared__ float P[8 * 9 * 18];

    const int tid  = threadIdx.x;
    const int b    = blockIdx.x >> 3;
    const int tile = blockIdx.x & 7;
    const int oh0  = (tile >> 1) << 2;
    const int ow0  = (tile & 1) << 3;

    for (int idx = tid; idx < 9216; idx += 256) {
        int oc = idx & 31, rest = idx >> 5;
        int ic = rest / 9, r9 = rest - ic * 9;
        wl[idx] = w3[(oc * 32 + ic) * 9 + r9];
    }

    const int ocg = tid >> 4, oc0 = ocg << 1;
    const int sl = tid & 15, r = sl >> 2, owp = sl & 3, owl = owp << 1;
    const float2 bias = *(const float2*)&b3[oc0];
    float pot[4];
    uint32_t om[4];
    #pragma unroll
    for (int i = 0; i < 4; i++) { pot[i] = 0.0f; om[i] = 0u; }

    for (int t = 0; t < 20; t++) {
        float acc[4];
        #pragma unroll
        for (int i = 0; i < 4; i++) acc[i] = 0.0f;
        for (int cc = 0; cc < 4; cc++) {
            __syncthreads();
            if (tid < 72) {
                int ic = tid / 9, ihl = tid - ic * 9;
                int ih = 2 * oh0 - 1 + ihl;
                uint32_t rowb = 0u;
                if (ih >= 0)
                    rowb = *(const uint32_t*)
                           &sp2[(((size_t)(t * 32 + b) * 32 + (cc * 8 + ic)) * 32 + ih) * 4];
                float* dst = &P[(ic * 9 + ihl) * 18];
                #pragma unroll
                for (int iwl = 0; iwl < 17; iwl++) {
                    int iw = 2 * ow0 - 1 + iwl;
                    int col = (iwl & 1) ? ((iwl - 1) >> 1) : (8 + (iwl >> 1));
                    dst[col] = (iw >= 0 && ((rowb >> iw) & 1u)) ? 1.0f : 0.0f;
                }
            }
            __syncthreads();
            #pragma unroll
            for (int ic = 0; ic < 8; ic++) {
                #pragma unroll
                for (int kh = 0; kh < 3; kh++) {
                    const float* row = &P[(ic * 9 + 2 * r + kh) * 18];
                    float eA = row[owl],     eB = row[owl + 1];
                    float oA = row[8 + owl], oB = row[9 + owl], oC = row[10 + owl];
                    const float* wb = &wl[((cc * 8 + ic) * 9 + kh * 3) * 32 + oc0];
                    float2 w0  = *(const float2*)(wb);
                    float2 w1v = *(const float2*)(wb + 32);
                    float2 w2v = *(const float2*)(wb + 64);
                    acc[0] += w0.x * oA;  acc[1] += w0.x * oB;
                    acc[2] += w0.y * oA;  acc[3] += w0.y * oB;
                    acc[0] += w1v.x * eA; acc[1] += w1v.x * eB;
                    acc[2] += w1v.y * eA; acc[3] += w1v.y * eB;
                    acc[0] += w2v.x * oB; acc[1] += w2v.x * oC;
                    acc[2] += w2v.y * oB; acc[3] += w2v.y * oC;
                }
            }
        }
        #pragma unroll
        for (int k = 0; k < 2; k++) {
            float bk = (k == 0) ? bias.x : bias.y;
            #pragma unroll
            for (int w = 0; w < 2; w++) {
                float conv = acc[k * 2 + w] + bk;
                float pp = pot[k * 2 + w];
                float u = (pp > TH) ? conv : (pp * DECAY + conv);
                pot[k * 2 + w] = u;
                if (u > TH) om[k * 2 + w] |= 1u << t;
            }
        }
    }

    #pragma unroll
    for (int k = 0; k < 2; k++) {
        #pragma unroll
        for (int w = 0; w < 2; w++) {
            int oc = oc0 + k;
            int oh = oh0 + r, ow = ow0 + owl + w;
            int i = (oc << 8) + (oh << 4) + ow;
            float* dst = &out[((size_t)b * 8192 + i) * 20];
            uint32_t m = om[k * 2 + w];
            #pragma unroll
            for (int qq = 0; qq < 5; qq++) {
                float4 v;
                v.x = ((m >> (qq * 4 + 0)) & 1u) ? 1.0f : 0.0f;
                v.y = ((m >> (qq * 4 + 1)) & 1u) ? 1.0f : 0.0f;
                v.z = ((m >> (qq * 4 + 2)) & 1u) ? 1.0f : 0.0f;
                v.w = ((m >> (qq * 4 + 3)) & 1u) ? 1.0f : 0.0f;
                *(float4*)&dst[qq * 4] = v;
            }
        }
    }
}

extern "C" void kernel_launch(void* const* d_in, const int* in_sizes, int n_in,
                              void* d_out, int out_size, void* d_ws, size_t ws_size,
                              hipStream_t stream)
{
    (void)in_sizes; (void)n_in; (void)out_size;
    const float* in = (const float*)d_in[0];
    const float* w1 = (const float*)d_in[1];
    const float* b1 = (const float*)d_in[2];
    const float* w2 = (const float*)d_in[3];
    const float* b2 = (const float*)d_in[4];
    const float* w3 = (const float*)d_in[5];
    const float* b3 = (const float*)d_in[6];

    const size_t SP1_BYTES = (size_t)20 * 32 * 32 * 64 * 8;    // 10,485,760
    const size_t SP2_BYTES = (size_t)20 * 32 * 32 * 32 * 4;    //  2,621,440
    const size_t S2_BYTES  = (size_t)20 * 32 * 32 * 1024 * 4;  // 83,886,080
    const size_t S3_BYTES  = (size_t)20 * 32 * 32 * 256 * 4;   // 20,971,520

    uint8_t* base = (uint8_t*)d_ws;
    const bool full = ws_size >= SP1_BYTES + SP2_BYTES + S2_BYTES;   // 97.0 MB
    const bool mid  = ws_size >= S3_BYTES + SP2_BYTES;               // 23.6 MB

    if (full) {
        uint8_t* sp1 = base;
        uint8_t* sp2 = base + SP1_BYTES;
        float*   S2  = (float*)(base + SP1_BYTES + SP2_BYTES);
        float*   S3  = (float*)(base + SP1_BYTES + SP2_BYTES);  // overlays dead S2
        k1_conv<<<32 * 64, 256, 0, stream>>>(in, w1, b1, sp1);
        k2a_conv<<<20 * 32 * 8, 256, 0, stream>>>(sp1, w2, S2);
        k2b_rec<<<32 * 32 * 4, 256, 0, stream>>>(S2, b2, sp2);
        k3a_conv<<<20 * 32 * 4, 256, 0, stream>>>(sp2, w3, S3);
        k3b_rec<<<32 * 32, 256, 0, stream>>>(S3, b3, (float*)d_out);
    } else if (mid) {
        uint8_t* sp1 = base;                 // dead before k3a writes S3
        float*   S3  = (float*)base;
        uint8_t* sp2 = base + S3_BYTES;
        k1_conv<<<32 * 64, 256, 0, stream>>>(in, w1, b1, sp1);
        k2_conv<<<32 * 16, 256, 0, stream>>>(sp1, w2, b2, sp2);
        k3a_conv<<<20 * 32 * 4, 256, 0, stream>>>(sp2, w3, S3);
        k3b_rec<<<32 * 32, 256, 0, stream>>>(S3, b3, (float*)d_out);
    } else {
        uint8_t* sp1 = base;
        uint8_t* sp2 = base + SP1_BYTES;
        k1_conv<<<32 * 64, 256, 0, stream>>>(in, w1, b1, sp1);
        k2_conv<<<32 * 16, 256, 0, stream>>>(sp1, w2, b2, sp2);
        k3_fused<<<32 * 8, 256, 0, stream>>>(sp2, w3, b3, (float*)d_out);
    }
}

// Round 5
// 532.854 us; speedup vs baseline: 2.6877x; 1.0830x over previous
//
#include <hip/hip_runtime.h>
#include <cstdint>

// SpikeModel: 3-layer stride-2 3x3 spiking CNN, T=20, bs=32.
// k1:  conv1 fused over t (pot in regs), full-width 1-row blocks. (r3)
// k2a: conv2 SUMS, parallel over (t,b,8-row band). Thread = 4oc x 8ow;
//      v_pk_fma_f32 packed over oc pairs (weights contiguous in LDS, tap
//      scalar broadcast via opsel). ~0.9 issue-slot/MAC vs 1.46 in r4.
// k2b: elementwise membrane recurrence, ballot -> sp2 bits. (r4)
// k3a: conv3 sums, same pk structure, 1 block = (t,b) whole 16x16 tile.
// k3b: recurrence + t-inner output. (r2)
// Fallbacks when ws is small: fused k2_conv (r3) / fused k3 (r1).
// EXACTNESS CONTRACT: every accumulator chain is fused-FMA in (ic asc,
// kh asc, kw asc) order, bias last — bit-identical to rounds 1-4 (absmax
// 0.0 four times). pk halves are independent chains. Do not reorder.

#define DECAY 0.2f
#define TH 0.5f

typedef float v2f __attribute__((ext_vector_type(2)));

static __device__ __forceinline__ v2f pk_fma(v2f a, v2f b, v2f c) {
#if __has_builtin(__builtin_elementwise_fma)
    return __builtin_elementwise_fma(a, b, c);
#else
    v2f r;
    r.x = __builtin_fmaf(a.x, b.x, c.x);
    r.y = __builtin_fmaf(a.y, b.y, c.y);
    return r;
#endif
}

// -------------------------------------------------------------------------
// Kernel 1: conv1 (IC=2, 128x128 -> OC=32, 64x64), grid 32*64, block 256.
// Block = (b, out-row). P[t][ic*3+ihl][136]: E cols at +0, O cols at +68.
// -------------------------------------------------------------------------
__global__ __launch_bounds__(256, 2)
void k1_conv(const float* __restrict__ in, const float* __restrict__ w1,
             const float* __restrict__ b1, uint8_t* __restrict__ sp1)
{
    __shared__ float P[20 * 816];   // 65,280 B

    const int tid = threadIdx.x;
    const int b   = blockIdx.x >> 6;
    const int row = blockIdx.x & 63;

    for (int idx = tid; idx < 3870; idx += 256) {
        int q = idx % 5, px = idx / 5;
        int iwl = px % 129, rest = px / 129;
        int ihl = rest % 3, ic = rest / 3;
        int ih = 2 * row - 1 + ihl;
        int iw = iwl - 1;
        float4 v = make_float4(0.f, 0.f, 0.f, 0.f);
        if (ih >= 0 && iw >= 0)
            v = *(const float4*)&in[(((size_t)(b * 2 + ic) * 128 + ih) * 128 + iw) * 20 + q * 4];
        int col = (iwl & 1) ? ((iwl - 1) >> 1) : (68 + (iwl >> 1));
        float* dst = &P[(ic * 3 + ihl) * 136 + col];
        int t0 = q * 4;
        dst[(t0 + 0) * 816] = v.x;
        dst[(t0 + 1) * 816] = v.y;
        dst[(t0 + 2) * 816] = v.z;
        dst[(t0 + 3) * 816] = v.w;
    }

    const int oc = tid >> 3;
    const int tw = tid & 7;

    float w[18];
    #pragma unroll
    for (int ic = 0; ic < 2; ic++)
        #pragma unroll
        for (int k9 = 0; k9 < 9; k9++)
            w[ic * 9 + k9] = w1[(oc * 2 + ic) * 9 + k9];
    const float bk = b1[oc];

    float pot[8];
    #pragma unroll
    for (int i = 0; i < 8; i++) pot[i] = 0.0f;

    __syncthreads();

    for (int t = 0; t < 20; t++) {
        float acc[8];
        #pragma unroll
        for (int i = 0; i < 8; i++) acc[i] = 0.0f;
        const float* Pt = &P[t * 816];
        #pragma unroll
        for (int ic = 0; ic < 2; ic++) {
            #pragma unroll
            for (int kh = 0; kh < 3; kh++) {
                const float* rowp = Pt + (ic * 3 + kh) * 136;
                float4 e0 = *(const float4*)&rowp[8 * tw];
                float4 e1 = *(const float4*)&rowp[8 * tw + 4];
                float4 o0 = *(const float4*)&rowp[68 + 8 * tw];
                float4 o1 = *(const float4*)&rowp[68 + 8 * tw + 4];
                float  o8 = rowp[68 + 8 * tw + 8];
                float wk0 = w[ic * 9 + kh * 3 + 0];
                float wk1 = w[ic * 9 + kh * 3 + 1];
                float wk2 = w[ic * 9 + kh * 3 + 2];
                acc[0] += wk0 * o0.x; acc[1] += wk0 * o0.y;
                acc[2] += wk0 * o0.z; acc[3] += wk0 * o0.w;
                acc[4] += wk0 * o1.x; acc[5] += wk0 * o1.y;
                acc[6] += wk0 * o1.z; acc[7] += wk0 * o1.w;
                acc[0] += wk1 * e0.x; acc[1] += wk1 * e0.y;
                acc[2] += wk1 * e0.z; acc[3] += wk1 * e0.w;
                acc[4] += wk1 * e1.x; acc[5] += wk1 * e1.y;
                acc[6] += wk1 * e1.z; acc[7] += wk1 * e1.w;
                acc[0] += wk2 * o0.y; acc[1] += wk2 * o0.z;
                acc[2] += wk2 * o0.w; acc[3] += wk2 * o1.x;
                acc[4] += wk2 * o1.y; acc[5] += wk2 * o1.z;
                acc[6] += wk2 * o1.w; acc[7] += wk2 * o8;
            }
        }
        uint32_t v = 0;
        #pragma unroll
        for (int j = 0; j < 8; j++) {
            float conv = acc[j] + bk;
            float pp = pot[j];
            float u = (pp > TH) ? conv : (pp * DECAY + conv);
            pot[j] = u;
            if (u > TH) v |= 1u << j;
        }
        sp1[(((size_t)(t * 32 + b) * 32 + oc) * 64 + row) * 8 + tw] = (uint8_t)v;
    }
}

// -------------------------------------------------------------------------
// Kernel 2a: conv2 sums (IC=32, 64x64 -> OC=32, 32x32), no recurrence.
// grid 20*32*4 (t, b, 8-row band), block 256.
// Thread = 4oc x 8ow: ocg=tid>>5, r=(tid>>2)&7, owq=tid&3 (ow0=8*owq).
// Packed fp32 FMA over oc pairs; per-iter: 1 b64 bits + 3 b128 weights
// + 17 bit-cvt + 48 pk_fma = 96 MACs.
// -------------------------------------------------------------------------
__global__ __launch_bounds__(256, 3)
void k2a_conv(const uint8_t* __restrict__ sp1, const float* __restrict__ w2,
              float* __restrict__ S2)
{
    __shared__ float wl[9216];                 // [ic][kh][kw][oc]  36,864 B
    __shared__ unsigned long long B[544];      // [ic][17 ihl rows]  4,352 B

    const int tid  = threadIdx.x;
    const int bid  = blockIdx.x;
    const int t    = bid >> 7;
    const int rem  = bid & 127;
    const int b    = rem >> 2;
    const int band = rem & 3;
    const int oh0  = band << 3;

    for (int idx = tid; idx < 9216; idx += 256) {
        int oc = idx & 31, rest = idx >> 5;
        int ic = rest / 9, r9 = rest - ic * 9;
        wl[idx] = w2[(oc * 32 + ic) * 9 + r9];
    }
    const unsigned long long* sp1w = (const unsigned long long*)sp1;
    for (int idx = tid; idx < 544; idx += 256) {
        int ic = idx / 17, ihl = idx - ic * 17;
        int ih = 2 * oh0 - 1 + ihl;
        B[idx] = (ih >= 0) ? sp1w[((size_t)(t * 32 + b) * 32 + ic) * 64 + ih] : 0ull;
    }
    __syncthreads();

    const int oc0 = (tid >> 5) << 2;
    const int r   = (tid >> 2) & 7;
    const int owq = tid & 3;
    const int sshift = 16 * owq - 1;     // -1 only when owq==0

    v2f acc[2][8];
    #pragma unroll
    for (int k = 0; k < 2; k++)
        #pragma unroll
        for (int j = 0; j < 8; j++) acc[k][j] = (v2f){0.0f, 0.0f};

    #pragma unroll 4
    for (int ic = 0; ic < 32; ic++) {
        #pragma unroll
        for (int kh = 0; kh < 3; kh++) {
            unsigned long long m = B[ic * 17 + 2 * r + kh];
            uint32_t bits = (sshift >= 0) ? (uint32_t)(m >> sshift)
                                          : (((uint32_t)m) << 1);
            float f[17];
            #pragma unroll
            for (int i = 0; i < 17; i++) f[i] = (float)((bits >> i) & 1u);
            const float* wb = &wl[(ic * 9 + kh * 3) * 32 + oc0];
            #pragma unroll
            for (int kw = 0; kw < 3; kw++) {
                v2f w01 = *(const v2f*)&wb[kw * 32];
                v2f w23 = *(const v2f*)&wb[kw * 32 + 2];
                #pragma unroll
                for (int j = 0; j < 8; j++) {
                    v2f fv = {f[2 * j + kw], f[2 * j + kw]};
                    acc[0][j] = pk_fma(w01, fv, acc[0][j]);
                    acc[1][j] = pk_fma(w23, fv, acc[1][j]);
                }
            }
        }
    }

    #pragma unroll
    for (int k = 0; k < 2; k++) {
        const int oc = oc0 + 2 * k;
        size_t base = ((size_t)(t * 32 + b) * 32 + oc) * 1024 + (oh0 + r) * 32 + owq * 8;
        float4 a0 = make_float4(acc[k][0].x, acc[k][1].x, acc[k][2].x, acc[k][3].x);
        float4 a1 = make_float4(acc[k][4].x, acc[k][5].x, acc[k][6].x, acc[k][7].x);
        float4 b0 = make_float4(acc[k][0].y, acc[k][1].y, acc[k][2].y, acc[k][3].y);
        float4 b1 = make_float4(acc[k][4].y, acc[k][5].y, acc[k][6].y, acc[k][7].y);
        *(float4*)&S2[base] = a0;
        *(float4*)&S2[base + 4] = a1;
        *(float4*)&S2[base + 1024] = b0;
        *(float4*)&S2[base + 1028] = b1;
    }
}

// -------------------------------------------------------------------------
// Kernel 2b: membrane recurrence for layer 2, grid 32*32*4, block 256.
// -------------------------------------------------------------------------
__global__ __launch_bounds__(256, 4)
void k2b_rec(const float* __restrict__ S2, const float* __restrict__ b2,
             uint8_t* __restrict__ sp2)
{
    const int bid = blockIdx.x;
    const int b   = bid >> 7;
    const int rem = bid & 127;
    const int oc  = rem >> 2;
    const int q   = rem & 3;
    const int tid = threadIdx.x;
    const int px  = q * 256 + tid;
    const float bk = b2[oc];
    uint32_t* sp2w = (uint32_t*)sp2;

    float sv[20];
    #pragma unroll
    for (int t = 0; t < 20; t++)
        sv[t] = S2[((size_t)(t * 32 + b) * 32 + oc) * 1024 + px];

    const int lane = tid & 63;
    float p = 0.0f;
    #pragma unroll
    for (int t = 0; t < 20; t++) {
        float conv = sv[t] + bk;
        float u = (p > TH) ? conv : (p * DECAY + conv);
        p = u;
        unsigned long long mk = __ballot(u > TH);
        if (lane == 0)
            sp2w[((size_t)(t * 32 + b) * 32 + oc) * 32 + (px >> 5)] = (uint32_t)mk;
        if (lane == 32)
            sp2w[((size_t)(t * 32 + b) * 32 + oc) * 32 + (px >> 5)] = (uint32_t)(mk >> 32);
    }
}

// -------------------------------------------------------------------------
// Kernel 3a: conv3 sums (IC=32, 32x32 -> OC=32, 16x16), grid 20*32.
// Block = (t,b), whole 16x16 tile. Thread = 4oc x 8ow:
// ocg=tid>>5, r=(tid>>1)&15, owq=tid&1. Same pk structure as k2a.
// -------------------------------------------------------------------------
__global__ __launch_bounds__(256, 3)
void k3a_conv(const uint8_t* __restrict__ sp2, const float* __restrict__ w3,
              float* __restrict__ S3)
{
    __shared__ float wl[9216];       // [ic][kh][kw][oc]  36,864 B
    __shared__ uint32_t Bs[1056];    // [ic][ih+1], slot 0 = zero pad

    const int bid = blockIdx.x;
    const int t   = bid >> 5;
    const int b   = bid & 31;
    const int tid = threadIdx.x;
    const uint32_t* sp2w = (const uint32_t*)sp2;

    for (int idx = tid; idx < 9216; idx += 256) {
        int oc = idx & 31, rest = idx >> 5;
        int ic = rest / 9, r9 = rest - ic * 9;
        wl[idx] = w3[(oc * 32 + ic) * 9 + r9];
    }
    for (int idx = tid; idx < 1056; idx += 256) {
        int ic = idx / 33, ihl = idx - ic * 33;
        int ih = ihl - 1;
        Bs[idx] = (ih >= 0) ? sp2w[((size_t)(t * 32 + b) * 32 + ic) * 32 + ih] : 0u;
    }
    __syncthreads();

    const int oc0 = (tid >> 5) << 2;
    const int r   = (tid >> 1) & 15;
    const int owq = tid & 1;

    v2f acc[2][8];
    #pragma unroll
    for (int k = 0; k < 2; k++)
        #pragma unroll
        for (int j = 0; j < 8; j++) acc[k][j] = (v2f){0.0f, 0.0f};

    #pragma unroll 4
    for (int ic = 0; ic < 32; ic++) {
        #pragma unroll
        for (int kh = 0; kh < 3; kh++) {
            uint32_t m = Bs[ic * 33 + 2 * r + kh];   // row ih = 2r-1+kh (padded)
            uint32_t bits = owq ? (m >> 15) : (m << 1);
            float f[17];
            #pragma unroll
            for (int i = 0; i < 17; i++) f[i] = (float)((bits >> i) & 1u);
            const float* wb = &wl[(ic * 9 + kh * 3) * 32 + oc0];
            #pragma unroll
            for (int kw = 0; kw < 3; kw++) {
                v2f w01 = *(const v2f*)&wb[kw * 32];
                v2f w23 = *(const v2f*)&wb[kw * 32 + 2];
                #pragma unroll
                for (int j = 0; j < 8; j++) {
                    v2f fv = {f[2 * j + kw], f[2 * j + kw]};
                    acc[0][j] = pk_fma(w01, fv, acc[0][j]);
                    acc[1][j] = pk_fma(w23, fv, acc[1][j]);
                }
            }
        }
    }

    #pragma unroll
    for (int k = 0; k < 2; k++) {
        const int oc = oc0 + 2 * k;
        size_t base = ((size_t)(t * 32 + b) * 32 + oc) * 256 + r * 16 + owq * 8;
        float4 a0 = make_float4(acc[k][0].x, acc[k][1].x, acc[k][2].x, acc[k][3].x);
        float4 a1 = make_float4(acc[k][4].x, acc[k][5].x, acc[k][6].x, acc[k][7].x);
        float4 b0 = make_float4(acc[k][0].y, acc[k][1].y, acc[k][2].y, acc[k][3].y);
        float4 b1 = make_float4(acc[k][4].y, acc[k][5].y, acc[k][6].y, acc[k][7].y);
        *(float4*)&S3[base] = a0;
        *(float4*)&S3[base + 4] = a1;
        *(float4*)&S3[base + 256] = b0;
        *(float4*)&S3[base + 260] = b1;
    }
}

// -------------------------------------------------------------------------
// Kernel 3 phase B: membrane recurrence + t-inner output, grid 32*32.
// -------------------------------------------------------------------------
__global__ __launch_bounds__(256, 4)
void k3b_rec(const float* __restrict__ S3, const float* __restrict__ b3,
             float* __restrict__ out)
{
    const int b  = blockIdx.x >> 5;
    const int oc = blockIdx.x & 31;
    const int tid = threadIdx.x;
    const float bk = b3[oc];

    float p = 0.0f;
    uint32_t om = 0u;
    for (int t = 0; t < 20; t++) {
        float s = S3[((size_t)(t * 32 + b) * 32 + oc) * 256 + tid];
        float conv = s + bk;
        float u = (p > TH) ? conv : (p * DECAY + conv);
        p = u;
        if (u > TH) om |= 1u << t;
    }
    float* dst = &out[((size_t)b * 8192 + (oc << 8) + tid) * 20];
    #pragma unroll
    for (int qq = 0; qq < 5; qq++) {
        float4 v;
        v.x = ((om >> (qq * 4 + 0)) & 1u) ? 1.0f : 0.0f;
        v.y = ((om >> (qq * 4 + 1)) & 1u) ? 1.0f : 0.0f;
        v.z = ((om >> (qq * 4 + 2)) & 1u) ? 1.0f : 0.0f;
        v.w = ((om >> (qq * 4 + 3)) & 1u) ? 1.0f : 0.0f;
        *(float4*)&dst[qq * 4] = v;
    }
}

// -------------------------------------------------------------------------
// Kernel 2 (FALLBACK, fused over t): round-3 version.
// -------------------------------------------------------------------------
__global__ __launch_bounds__(256, 2)
void k2_conv(const uint8_t* __restrict__ sp1, const float* __restrict__ w2,
             const float* __restrict__ b2, uint8_t* __restrict__ sp2)
{
    __shared__ float wl[9216];
    __shared__ unsigned long long B[544];

    const int tid  = threadIdx.x;
    const int b    = blockIdx.x >> 4;
    const int tile = blockIdx.x & 15;
    const int oh0  = (tile >> 2) << 3;
    const int ow0  = (tile & 3) << 3;

    for (int idx = tid; idx < 9216; idx += 256) {
        int oc = idx & 31, rest = idx >> 5;
        int ic = rest / 9, r9 = rest - ic * 9;
        wl[idx] = w2[(oc * 32 + ic) * 9 + r9];
    }

    const unsigned long long* sp1w = (const unsigned long long*)sp1;
    int w0i = tid, w1i = 256 + tid, w2i = 512 + tid;
    int ic0s = w0i / 17, ih0 = 2 * oh0 - 1 + (w0i - ic0s * 17);
    int ic1s = w1i / 17, ih1 = 2 * oh0 - 1 + (w1i - ic1s * 17);
    int ic2s = w2i / 17, ih2 = 2 * oh0 - 1 + (w2i - ic2s * 17);
    const size_t base0 = (size_t)(b * 32 + ic0s) * 64 + ih0;
    const size_t base1 = (size_t)(b * 32 + ic1s) * 64 + ih1;
    const size_t base2 = (size_t)(b * 32 + ic2s) * 64 + ih2;
    const bool v0ok = (ih0 >= 0), v1ok = (ih1 >= 0), v2ok = (tid < 32) && (ih2 >= 0);

    unsigned long long v0 = v0ok ? sp1w[base0] : 0ull;
    unsigned long long v1 = v1ok ? sp1w[base1] : 0ull;
    unsigned long long v2 = v2ok ? sp1w[base2] : 0ull;

    const int oc0 = (tid >> 5) << 2;
    const int sl  = tid & 31;
    const int r   = sl >> 2;
    const int owp = sl & 3, owl = owp << 1;
    const int sshift = 2 * (ow0 + owl) - 1;

    const float4 bias = *(const float4*)&b2[oc0];
    float pot[8];
    #pragma unroll
    for (int i = 0; i < 8; i++) pot[i] = 0.0f;

    for (int t = 0; t < 20; t++) {
        __syncthreads();
        B[tid] = v0;
        B[256 + tid] = v1;
        if (tid < 32) B[512 + tid] = v2;
        __syncthreads();
        if (t < 19) {
            size_t ts = (size_t)(t + 1) * 65536;
            v0 = v0ok ? sp1w[ts + base0] : 0ull;
            v1 = v1ok ? sp1w[ts + base1] : 0ull;
            v2 = v2ok ? sp1w[ts + base2] : 0ull;
        }

        float acc[8];
        #pragma unroll
        for (int i = 0; i < 8; i++) acc[i] = 0.0f;
        const unsigned long long* Bp = &B[2 * r];
        #pragma unroll 4
        for (int ic = 0; ic < 32; ic++) {
            #pragma unroll
            for (int kh = 0; kh < 3; kh++) {
                unsigned long long m = Bp[ic * 17 + kh];
                uint32_t bits = (sshift >= 0) ? (uint32_t)(m >> sshift)
                                              : (((uint32_t)m) << 1);
                float f0 = (float)(bits & 1u);
                float f1 = (float)((bits >> 1) & 1u);
                float f2 = (float)((bits >> 2) & 1u);
                float f3 = (float)((bits >> 3) & 1u);
                float f4 = (float)((bits >> 4) & 1u);
                const float* wb = &wl[(ic * 9 + kh * 3) * 32 + oc0];
                float4 wk0 = *(const float4*)(wb);
                float4 wk1 = *(const float4*)(wb + 32);
                float4 wk2 = *(const float4*)(wb + 64);
                acc[0] += wk0.x * f0;  acc[1] += wk0.x * f2;
                acc[2] += wk0.y * f0;  acc[3] += wk0.y * f2;
                acc[4] += wk0.z * f0;  acc[5] += wk0.z * f2;
                acc[6] += wk0.w * f0;  acc[7] += wk0.w * f2;
                acc[0] += wk1.x * f1;  acc[1] += wk1.x * f3;
                acc[2] += wk1.y * f1;  acc[3] += wk1.y * f3;
                acc[4] += wk1.z * f1;  acc[5] += wk1.z * f3;
                acc[6] += wk1.w * f1;  acc[7] += wk1.w * f3;
                acc[0] += wk2.x * f2;  acc[1] += wk2.x * f4;
                acc[2] += wk2.y * f2;  acc[3] += wk2.y * f4;
                acc[4] += wk2.z * f2;  acc[5] += wk2.z * f4;
                acc[6] += wk2.w * f2;  acc[7] += wk2.w * f4;
            }
        }

        uint32_t p = 0;
        #pragma unroll
        for (int k = 0; k < 4; k++) {
            float bkk = ((const float*)&bias)[k];
            uint32_t v = 0;
            #pragma unroll
            for (int w = 0; w < 2; w++) {
                float conv = acc[k * 2 + w] + bkk;
                float pp = pot[k * 2 + w];
                float u = (pp > TH) ? conv : (pp * DECAY + conv);
                pot[k * 2 + w] = u;
                if (u > TH) v |= 1u << (owl + w);
            }
            p |= v << (8 * k);
        }
        p |= __shfl_xor((int)p, 1);
        p |= __shfl_xor((int)p, 2);
        if (owp == 0) {
            #pragma unroll
            for (int k = 0; k < 4; k++)
                sp2[(((size_t)(t * 32 + b) * 32 + (oc0 + k)) * 32 + (oh0 + r)) * 4 + (ow0 >> 3)]
                    = (uint8_t)(p >> (8 * k));
        }
    }
}

// -------------------------------------------------------------------------
// Fallback fused k3 if ws is too small for S3.
// -------------------------------------------------------------------------
__global__ __launch_bounds__(256, 3)
void k3_fused(const uint8_t* __restrict__ sp2, const float* __restrict__ w3,
              const float* __restrict__ b3, float* __restrict__ out)
{
    __shared__ float wl[9216];
    __shared__ float P[8 * 9 * 18];

    const int tid  = threadIdx.x;
    const int b    = blockIdx.x >> 3;
    const int tile = blockIdx.x & 7;
    const int oh0  = (tile >> 1) << 2;
    const int ow0  = (tile & 1) << 3;

    for (int idx = tid; idx < 9216; idx += 256) {
        int oc = idx & 31, rest = idx >> 5;
        int ic = rest / 9, r9 = rest - ic * 9;
        wl[idx] = w3[(oc * 32 + ic) * 9 + r9];
    }

    const int ocg = tid >> 4, oc0 = ocg << 1;
    const int sl = tid & 15, r = sl >> 2, owp = sl & 3, owl = owp << 1;
    const float2 bias = *(const float2*)&b3[oc0];
    float pot[4];
    uint32_t om[4];
    #pragma unroll
    for (int i = 0; i < 4; i++) { pot[i] = 0.0f; om[i] = 0u; }

    for (int t = 0; t < 20; t++) {
        float acc[4];
        #pragma unroll
        for (int i = 0; i < 4; i++) acc[i] = 0.0f;
        for (int cc = 0; cc < 4; cc++) {
            __syncthreads();
            if (tid < 72) {
                int ic = tid / 9, ihl = tid - ic * 9;
                int ih = 2 * oh0 - 1 + ihl;
                uint32_t rowb = 0u;
                if (ih >= 0)
                    rowb = *(const uint32_t*)
                           &sp2[(((size_t)(t * 32 + b) * 32 + (cc * 8 + ic)) * 32 + ih) * 4];
                float* dst = &P[(ic * 9 + ihl) * 18];
                #pragma unroll
                for (int iwl = 0; iwl < 17; iwl++) {
                    int iw = 2 * ow0 - 1 + iwl;
                    int col = (iwl & 1) ? ((iwl - 1) >> 1) : (8 + (iwl >> 1));
                    dst[col] = (iw >= 0 && ((rowb >> iw) & 1u)) ? 1.0f : 0.0f;
                }
            }
            __syncthreads();
            #pragma unroll
            for (int ic = 0; ic < 8; ic++) {
                #pragma unroll
                for (int kh = 0; kh < 3; kh++) {
                    const float* row = &P[(ic * 9 + 2 * r + kh) * 18];
                    float eA = row[owl],     eB = row[owl + 1];
                    float oA = row[8 + owl], oB = row[9 + owl], oC = row[10 + owl];
                    const float* wb = &wl[((cc * 8 + ic) * 9 + kh * 3) * 32 + oc0];
                    float2 w0  = *(const float2*)(wb);
                    float2 w1v = *(const float2*)(wb + 32);
                    float2 w2v = *(const float2*)(wb + 64);
                    acc[0] += w0.x * oA;  acc[1] += w0.x * oB;
                    acc[2] += w0.y * oA;  acc[3] += w0.y * oB;
                    acc[0] += w1v.x * eA; acc[1] += w1v.x * eB;
                    acc[2] += w1v.y * eA; acc[3] += w1v.y * eB;
                    acc[0] += w2v.x * oB; acc[1] += w2v.x * oC;
                    acc[2] += w2v.y * oB; acc[3] += w2v.y * oC;
                }
            }
        }
        #pragma unroll
        for (int k = 0; k < 2; k++) {
            float bk = (k == 0) ? bias.x : bias.y;
            #pragma unroll
            for (int w = 0; w < 2; w++) {
                float conv = acc[k * 2 + w] + bk;
                float pp = pot[k * 2 + w];
                float u = (pp > TH) ? conv : (pp * DECAY + conv);
                pot[k * 2 + w] = u;
                if (u > TH) om[k * 2 + w] |= 1u << t;
            }
        }
    }

    #pragma unroll
    for (int k = 0; k < 2; k++) {
        #pragma unroll
        for (int w = 0; w < 2; w++) {
            int oc = oc0 + k;
            int oh = oh0 + r, ow = ow0 + owl + w;
            int i = (oc << 8) + (oh << 4) + ow;
            float* dst = &out[((size_t)b * 8192 + i) * 20];
            uint32_t m = om[k * 2 + w];
            #pragma unroll
            for (int qq = 0; qq < 5; qq++) {
                float4 v;
                v.x = ((m >> (qq * 4 + 0)) & 1u) ? 1.0f : 0.0f;
                v.y = ((m >> (qq * 4 + 1)) & 1u) ? 1.0f : 0.0f;
                v.z = ((m >> (qq * 4 + 2)) & 1u) ? 1.0f : 0.0f;
                v.w = ((m >> (qq * 4 + 3)) & 1u) ? 1.0f : 0.0f;
                *(float4*)&dst[qq * 4] = v;
            }
        }
    }
}

extern "C" void kernel_launch(void* const* d_in, const int* in_sizes, int n_in,
                              void* d_out, int out_size, void* d_ws, size_t ws_size,
                              hipStream_t stream)
{
    (void)in_sizes; (void)n_in; (void)out_size;
    const float* in = (const float*)d_in[0];
    const float* w1 = (const float*)d_in[1];
    const float* b1 = (const float*)d_in[2];
    const float* w2 = (const float*)d_in[3];
    const float* b2 = (const float*)d_in[4];
    const float* w3 = (const float*)d_in[5];
    const float* b3 = (const float*)d_in[6];

    const size_t SP1_BYTES = (size_t)20 * 32 * 32 * 64 * 8;    // 10,485,760
    const size_t SP2_BYTES = (size_t)20 * 32 * 32 * 32 * 4;    //  2,621,440
    const size_t S2_BYTES  = (size_t)20 * 32 * 32 * 1024 * 4;  // 83,886,080
    const size_t S3_BYTES  = (size_t)20 * 32 * 32 * 256 * 4;   // 20,971,520

    uint8_t* base = (uint8_t*)d_ws;
    const bool full = ws_size >= SP1_BYTES + SP2_BYTES + S2_BYTES;   // 97.0 MB
    const bool mid  = ws_size >= S3_BYTES + SP2_BYTES;               // 23.6 MB

    if (full) {
        uint8_t* sp1 = base;
        uint8_t* sp2 = base + SP1_BYTES;
        float*   S2  = (float*)(base + SP1_BYTES + SP2_BYTES);
        float*   S3  = (float*)(base + SP1_BYTES + SP2_BYTES);  // overlays dead S2
        k1_conv<<<32 * 64, 256, 0, stream>>>(in, w1, b1, sp1);
        k2a_conv<<<20 * 32 * 4, 256, 0, stream>>>(sp1, w2, S2);
        k2b_rec<<<32 * 32 * 4, 256, 0, stream>>>(S2, b2, sp2);
        k3a_conv<<<20 * 32, 256, 0, stream>>>(sp2, w3, S3);
        k3b_rec<<<32 * 32, 256, 0, stream>>>(S3, b3, (float*)d_out);
    } else if (mid) {
        uint8_t* sp1 = base;                 // dead before k3a writes S3
        float*   S3  = (float*)base;
        uint8_t* sp2 = base + S3_BYTES;
        k1_conv<<<32 * 64, 256, 0, stream>>>(in, w1, b1, sp1);
        k2_conv<<<32 * 16, 256, 0, stream>>>(sp1, w2, b2, sp2);
        k3a_conv<<<20 * 32, 256, 0, stream>>>(sp2, w3, S3);
        k3b_rec<<<32 * 32, 256, 0, stream>>>(S3, b3, (float*)d_out);
    } else {
        uint8_t* sp1 = base;
        uint8_t* sp2 = base + SP1_BYTES;
        k1_conv<<<32 * 64, 256, 0, stream>>>(in, w1, b1, sp1);
        k2_conv<<<32 * 16, 256, 0, stream>>>(sp1, w2, b2, sp2);
        k3_fused<<<32 * 8, 256, 0, stream>>>(sp2, w3, b3, (float*)d_out);
    }
}

// Round 6
// 485.071 us; speedup vs baseline: 2.9524x; 1.0985x over previous
//
#include <hip/hip_runtime.h>
#include <cstdint>

// SpikeModel: 3-layer stride-2 3x3 spiking CNN, T=20, bs=32.
// k1:  conv1 fused over t (pot in regs), full-width 1-row blocks. (r3)
// wt_prep: transpose weights to [ocg][ic][kh][kw][8oc] for SGPR streaming.
// k2a: conv2 SUMS, wave-uniform ocg: thread = 8oc x 8ow, weights via
//      s_load (SGPR operand of v_pk_fma_f32 inline asm), bits-only LDS.
// k2b: elementwise membrane recurrence, ballot -> sp2 bits. (r4)
// k3a: conv3 sums, same wave-uniform structure (thread = 8oc x 4ow).
// k3b: recurrence + t-inner output. (r2)
// Fallbacks when ws is small: fused k2_conv (r3) / fused k3 (r1).
// EXACTNESS CONTRACT: every accumulator chain is fused-FMA in (ic asc,
// kh asc, kw asc) order, bias last — bit-identical to rounds 1-5 (absmax
// 0.0 five times). pk halves are independent chains. Do not reorder.

#define DECAY 0.2f
#define TH 0.5f

typedef float v2f __attribute__((ext_vector_type(2)));

// acc = w*f + acc, packed: w expected in SGPR pair (wave-uniform weights),
// f is a genuine {f,f} VGPR pair. Two independent IEEE fp32 FMA chains.
static __device__ __forceinline__ v2f pk_fma_sv(v2f w, v2f f, v2f acc) {
    asm("v_pk_fma_f32 %0, %1, %2, %0" : "+v"(acc) : "s"(w), "v"(f));
    return acc;
}

// -------------------------------------------------------------------------
// Weight transpose: wt[((ocg*32+ic)*9+r9)*8+ocl] = w[((ocg*8+ocl)*32+ic)*9+r9]
// -------------------------------------------------------------------------
__global__ __launch_bounds__(256, 4)
void wt_prep(const float* __restrict__ w, float* __restrict__ wt)
{
    int idx = blockIdx.x * 256 + threadIdx.x;
    if (idx < 9216) {
        int ocl = idx & 7;
        int r9  = (idx >> 3) % 9;
        int icg = idx / 72;
        int ic  = icg & 31;
        int ocg = icg >> 5;
        wt[idx] = w[((ocg * 8 + ocl) * 32 + ic) * 9 + r9];
    }
}

// -------------------------------------------------------------------------
// Kernel 1: conv1 (IC=2, 128x128 -> OC=32, 64x64), grid 32*64, block 256.
// Block = (b, out-row). P[t][ic*3+ihl][136]: E cols at +0, O cols at +68.
// -------------------------------------------------------------------------
__global__ __launch_bounds__(256, 2)
void k1_conv(const float* __restrict__ in, const float* __restrict__ w1,
             const float* __restrict__ b1, uint8_t* __restrict__ sp1)
{
    __shared__ float P[20 * 816];   // 65,280 B

    const int tid = threadIdx.x;
    const int b   = blockIdx.x >> 6;
    const int row = blockIdx.x & 63;

    for (int idx = tid; idx < 3870; idx += 256) {
        int q = idx % 5, px = idx / 5;
        int iwl = px % 129, rest = px / 129;
        int ihl = rest % 3, ic = rest / 3;
        int ih = 2 * row - 1 + ihl;
        int iw = iwl - 1;
        float4 v = make_float4(0.f, 0.f, 0.f, 0.f);
        if (ih >= 0 && iw >= 0)
            v = *(const float4*)&in[(((size_t)(b * 2 + ic) * 128 + ih) * 128 + iw) * 20 + q * 4];
        int col = (iwl & 1) ? ((iwl - 1) >> 1) : (68 + (iwl >> 1));
        float* dst = &P[(ic * 3 + ihl) * 136 + col];
        int t0 = q * 4;
        dst[(t0 + 0) * 816] = v.x;
        dst[(t0 + 1) * 816] = v.y;
        dst[(t0 + 2) * 816] = v.z;
        dst[(t0 + 3) * 816] = v.w;
    }

    const int oc = tid >> 3;
    const int tw = tid & 7;

    float w[18];
    #pragma unroll
    for (int ic = 0; ic < 2; ic++)
        #pragma unroll
        for (int k9 = 0; k9 < 9; k9++)
            w[ic * 9 + k9] = w1[(oc * 2 + ic) * 9 + k9];
    const float bk = b1[oc];

    float pot[8];
    #pragma unroll
    for (int i = 0; i < 8; i++) pot[i] = 0.0f;

    __syncthreads();

    for (int t = 0; t < 20; t++) {
        float acc[8];
        #pragma unroll
        for (int i = 0; i < 8; i++) acc[i] = 0.0f;
        const float* Pt = &P[t * 816];
        #pragma unroll
        for (int ic = 0; ic < 2; ic++) {
            #pragma unroll
            for (int kh = 0; kh < 3; kh++) {
                const float* rowp = Pt + (ic * 3 + kh) * 136;
                float4 e0 = *(const float4*)&rowp[8 * tw];
                float4 e1 = *(const float4*)&rowp[8 * tw + 4];
                float4 o0 = *(const float4*)&rowp[68 + 8 * tw];
                float4 o1 = *(const float4*)&rowp[68 + 8 * tw + 4];
                float  o8 = rowp[68 + 8 * tw + 8];
                float wk0 = w[ic * 9 + kh * 3 + 0];
                float wk1 = w[ic * 9 + kh * 3 + 1];
                float wk2 = w[ic * 9 + kh * 3 + 2];
                acc[0] += wk0 * o0.x; acc[1] += wk0 * o0.y;
                acc[2] += wk0 * o0.z; acc[3] += wk0 * o0.w;
                acc[4] += wk0 * o1.x; acc[5] += wk0 * o1.y;
                acc[6] += wk0 * o1.z; acc[7] += wk0 * o1.w;
                acc[0] += wk1 * e0.x; acc[1] += wk1 * e0.y;
                acc[2] += wk1 * e0.z; acc[3] += wk1 * e0.w;
                acc[4] += wk1 * e1.x; acc[5] += wk1 * e1.y;
                acc[6] += wk1 * e1.z; acc[7] += wk1 * e1.w;
                acc[0] += wk2 * o0.y; acc[1] += wk2 * o0.z;
                acc[2] += wk2 * o0.w; acc[3] += wk2 * o1.x;
                acc[4] += wk2 * o1.y; acc[5] += wk2 * o1.z;
                acc[6] += wk2 * o1.w; acc[7] += wk2 * o8;
            }
        }
        uint32_t v = 0;
        #pragma unroll
        for (int j = 0; j < 8; j++) {
            float conv = acc[j] + bk;
            float pp = pot[j];
            float u = (pp > TH) ? conv : (pp * DECAY + conv);
            pot[j] = u;
            if (u > TH) v |= 1u << j;
        }
        sp1[(((size_t)(t * 32 + b) * 32 + oc) * 64 + row) * 8 + tw] = (uint8_t)v;
    }
}

// -------------------------------------------------------------------------
// Kernel 2a: conv2 sums (IC=32, 64x64 -> OC=32, 32x32), no recurrence.
// grid 20*32*2 (t, b, 16-row band), block 256.
// Wave = ocg (8 oc); lane: r = lane>>2 (16 rows), owq = lane&3 (8 ow).
// Weights streamed from w2t via wave-uniform s_load into SGPR pk_fma src.
// -------------------------------------------------------------------------
__global__ __launch_bounds__(256, 4)
void k2a_conv(const uint8_t* __restrict__ sp1, const float* __restrict__ w2t,
              float* __restrict__ S2)
{
    __shared__ unsigned long long B[1056];     // [ic][33 rows], 8,448 B

    const int tid  = threadIdx.x;
    const int bid  = blockIdx.x;
    const int t    = bid >> 6;
    const int rem  = bid & 63;
    const int b    = rem >> 1;
    const int band = rem & 1;
    const int oh0  = band << 4;

    const unsigned long long* sp1w = (const unsigned long long*)sp1;
    for (int idx = tid; idx < 1056; idx += 256) {
        int ic = idx / 33, ihl = idx - ic * 33;
        int ih = 2 * oh0 - 1 + ihl;
        B[idx] = (ih >= 0) ? sp1w[((size_t)(t * 32 + b) * 32 + ic) * 64 + ih] : 0ull;
    }
    __syncthreads();

    const int ocgu = __builtin_amdgcn_readfirstlane(tid >> 6);
    const int lane = tid & 63;
    const int r    = lane >> 2;
    const int owq  = lane & 3;
    const float* wt = w2t + ocgu * 2304;       // [ic][9][8]

    v2f acc[4][8];
    #pragma unroll
    for (int k = 0; k < 4; k++)
        #pragma unroll
        for (int j = 0; j < 8; j++) acc[k][j] = (v2f){0.0f, 0.0f};

    #pragma unroll 2
    for (int ic = 0; ic < 32; ic++) {
        #pragma unroll
        for (int kh = 0; kh < 3; kh++) {
            unsigned long long m = B[ic * 33 + 2 * r + kh];
            uint32_t bits = owq ? (uint32_t)(m >> (16 * owq - 1))
                                : (((uint32_t)m) << 1);
            v2f fp[17];
            #pragma unroll
            for (int i = 0; i < 17; i++) {
                float fv = (float)((bits >> i) & 1u);
                fp[i] = (v2f){fv, fv};
            }
            const float* wp = wt + (ic * 9 + kh * 3) * 8;
            #pragma unroll
            for (int kw = 0; kw < 3; kw++) {
                #pragma unroll
                for (int ocp = 0; ocp < 4; ocp++) {
                    v2f wv = *(const v2f*)(wp + kw * 8 + 2 * ocp);
                    #pragma unroll
                    for (int j = 0; j < 8; j++)
                        acc[ocp][j] = pk_fma_sv(wv, fp[2 * j + kw], acc[ocp][j]);
                }
            }
        }
    }

    #pragma unroll
    for (int ocp = 0; ocp < 4; ocp++) {
        const int oc = ocgu * 8 + 2 * ocp;
        size_t base = ((size_t)(t * 32 + b) * 32 + oc) * 1024 + (oh0 + r) * 32 + owq * 8;
        float4 x0 = make_float4(acc[ocp][0].x, acc[ocp][1].x, acc[ocp][2].x, acc[ocp][3].x);
        float4 x1 = make_float4(acc[ocp][4].x, acc[ocp][5].x, acc[ocp][6].x, acc[ocp][7].x);
        float4 y0 = make_float4(acc[ocp][0].y, acc[ocp][1].y, acc[ocp][2].y, acc[ocp][3].y);
        float4 y1 = make_float4(acc[ocp][4].y, acc[ocp][5].y, acc[ocp][6].y, acc[ocp][7].y);
        *(float4*)&S2[base] = x0;
        *(float4*)&S2[base + 4] = x1;
        *(float4*)&S2[base + 1024] = y0;
        *(float4*)&S2[base + 1028] = y1;
    }
}

// -------------------------------------------------------------------------
// Kernel 2b: membrane recurrence for layer 2, grid 32*32*4, block 256.
// -------------------------------------------------------------------------
__global__ __launch_bounds__(256, 4)
void k2b_rec(const float* __restrict__ S2, const float* __restrict__ b2,
             uint8_t* __restrict__ sp2)
{
    const int bid = blockIdx.x;
    const int b   = bid >> 7;
    const int rem = bid & 127;
    const int oc  = rem >> 2;
    const int q   = rem & 3;
    const int tid = threadIdx.x;
    const int px  = q * 256 + tid;
    const float bk = b2[oc];
    uint32_t* sp2w = (uint32_t*)sp2;

    float sv[20];
    #pragma unroll
    for (int t = 0; t < 20; t++)
        sv[t] = S2[((size_t)(t * 32 + b) * 32 + oc) * 1024 + px];

    const int lane = tid & 63;
    float p = 0.0f;
    #pragma unroll
    for (int t = 0; t < 20; t++) {
        float conv = sv[t] + bk;
        float u = (p > TH) ? conv : (p * DECAY + conv);
        p = u;
        unsigned long long mk = __ballot(u > TH);
        if (lane == 0)
            sp2w[((size_t)(t * 32 + b) * 32 + oc) * 32 + (px >> 5)] = (uint32_t)mk;
        if (lane == 32)
            sp2w[((size_t)(t * 32 + b) * 32 + oc) * 32 + (px >> 5)] = (uint32_t)(mk >> 32);
    }
}

// -------------------------------------------------------------------------
// Kernel 3a: conv3 sums (IC=32, 32x32 -> OC=32, 16x16), grid 20*32.
// Wave = ocg (8 oc); lane: r = lane>>2 (16 rows), owq = lane&3 (4 ow).
// -------------------------------------------------------------------------
__global__ __launch_bounds__(256, 4)
void k3a_conv(const uint8_t* __restrict__ sp2, const float* __restrict__ w3t,
              float* __restrict__ S3)
{
    __shared__ uint32_t Bs[1056];    // [ic][33 rows], 4,224 B

    const int bid = blockIdx.x;
    const int t   = bid >> 5;
    const int b   = bid & 31;
    const int tid = threadIdx.x;
    const uint32_t* sp2w = (const uint32_t*)sp2;

    for (int idx = tid; idx < 1056; idx += 256) {
        int ic = idx / 33, ihl = idx - ic * 33;
        int ih = ihl - 1;
        Bs[idx] = (ih >= 0) ? sp2w[((size_t)(t * 32 + b) * 32 + ic) * 32 + ih] : 0u;
    }
    __syncthreads();

    const int ocgu = __builtin_amdgcn_readfirstlane(tid >> 6);
    const int lane = tid & 63;
    const int r    = lane >> 2;
    const int owq  = lane & 3;
    const float* wt = w3t + ocgu * 2304;

    v2f acc[4][4];
    #pragma unroll
    for (int k = 0; k < 4; k++)
        #pragma unroll
        for (int j = 0; j < 4; j++) acc[k][j] = (v2f){0.0f, 0.0f};

    #pragma unroll 2
    for (int ic = 0; ic < 32; ic++) {
        #pragma unroll
        for (int kh = 0; kh < 3; kh++) {
            uint32_t m = Bs[ic * 33 + 2 * r + kh];
            uint32_t bits = owq ? (m >> (8 * owq - 1)) : (m << 1);
            v2f fp[9];
            #pragma unroll
            for (int i = 0; i < 9; i++) {
                float fv = (float)((bits >> i) & 1u);
                fp[i] = (v2f){fv, fv};
            }
            const float* wp = wt + (ic * 9 + kh * 3) * 8;
            #pragma unroll
            for (int kw = 0; kw < 3; kw++) {
                #pragma unroll
                for (int ocp = 0; ocp < 4; ocp++) {
                    v2f wv = *(const v2f*)(wp + kw * 8 + 2 * ocp);
                    #pragma unroll
                    for (int j = 0; j < 4; j++)
                        acc[ocp][j] = pk_fma_sv(wv, fp[2 * j + kw], acc[ocp][j]);
                }
            }
        }
    }

    #pragma unroll
    for (int ocp = 0; ocp < 4; ocp++) {
        const int oc = ocgu * 8 + 2 * ocp;
        size_t base = ((size_t)(t * 32 + b) * 32 + oc) * 256 + r * 16 + owq * 4;
        float4 x0 = make_float4(acc[ocp][0].x, acc[ocp][1].x, acc[ocp][2].x, acc[ocp][3].x);
        float4 y0 = make_float4(acc[ocp][0].y, acc[ocp][1].y, acc[ocp][2].y, acc[ocp][3].y);
        *(float4*)&S3[base] = x0;
        *(float4*)&S3[base + 256] = y0;
    }
}

// -------------------------------------------------------------------------
// Kernel 3 phase B: membrane recurrence + t-inner output, grid 32*32.
// -------------------------------------------------------------------------
__global__ __launch_bounds__(256, 4)
void k3b_rec(const float* __restrict__ S3, const float* __restrict__ b3,
             float* __restrict__ out)
{
    const int b  = blockIdx.x >> 5;
    const int oc = blockIdx.x & 31;
    const int tid = threadIdx.x;
    const float bk = b3[oc];

    float p = 0.0f;
    uint32_t om = 0u;
    for (int t = 0; t < 20; t++) {
        float s = S3[((size_t)(t * 32 + b) * 32 + oc) * 256 + tid];
        float conv = s + bk;
        float u = (p > TH) ? conv : (p * DECAY + conv);
        p = u;
        if (u > TH) om |= 1u << t;
    }
    float* dst = &out[((size_t)b * 8192 + (oc << 8) + tid) * 20];
    #pragma unroll
    for (int qq = 0; qq < 5; qq++) {
        float4 v;
        v.x = ((om >> (qq * 4 + 0)) & 1u) ? 1.0f : 0.0f;
        v.y = ((om >> (qq * 4 + 1)) & 1u) ? 1.0f : 0.0f;
        v.z = ((om >> (qq * 4 + 2)) & 1u) ? 1.0f : 0.0f;
        v.w = ((om >> (qq * 4 + 3)) & 1u) ? 1.0f : 0.0f;
        *(float4*)&dst[qq * 4] = v;
    }
}

// -------------------------------------------------------------------------
// Kernel 2 (FALLBACK, fused over t): round-3 version.
// -------------------------------------------------------------------------
__global__ __launch_bounds__(256, 2)
void k2_conv(const uint8_t* __restrict__ sp1, const float* __restrict__ w2,
             const float* __restrict__ b2, uint8_t* __restrict__ sp2)
{
    __shared__ float wl[9216];
    __shared__ unsigned long long B[544];

    const int tid  = threadIdx.x;
    const int b    = blockIdx.x >> 4;
    const int tile = blockIdx.x & 15;
    const int oh0  = (tile >> 2) << 3;
    const int ow0  = (tile & 3) << 3;

    for (int idx = tid; idx < 9216; idx += 256) {
        int oc = idx & 31, rest = idx >> 5;
        int ic = rest / 9, r9 = rest - ic * 9;
        wl[idx] = w2[(oc * 32 + ic) * 9 + r9];
    }

    const unsigned long long* sp1w = (const unsigned long long*)sp1;
    int w0i = tid, w1i = 256 + tid, w2i = 512 + tid;
    int ic0s = w0i / 17, ih0 = 2 * oh0 - 1 + (w0i - ic0s * 17);
    int ic1s = w1i / 17, ih1 = 2 * oh0 - 1 + (w1i - ic1s * 17);
    int ic2s = w2i / 17, ih2 = 2 * oh0 - 1 + (w2i - ic2s * 17);
    const size_t base0 = (size_t)(b * 32 + ic0s) * 64 + ih0;
    const size_t base1 = (size_t)(b * 32 + ic1s) * 64 + ih1;
    const size_t base2 = (size_t)(b * 32 + ic2s) * 64 + ih2;
    const bool v0ok = (ih0 >= 0), v1ok = (ih1 >= 0), v2ok = (tid < 32) && (ih2 >= 0);

    unsigned long long v0 = v0ok ? sp1w[base0] : 0ull;
    unsigned long long v1 = v1ok ? sp1w[base1] : 0ull;
    unsigned long long v2 = v2ok ? sp1w[base2] : 0ull;

    const int oc0 = (tid >> 5) << 2;
    const int sl  = tid & 31;
    const int r   = sl >> 2;
    const int owp = sl & 3, owl = owp << 1;
    const int sshift = 2 * (ow0 + owl) - 1;

    const float4 bias = *(const float4*)&b2[oc0];
    float pot[8];
    #pragma unroll
    for (int i = 0; i < 8; i++) pot[i] = 0.0f;

    for (int t = 0; t < 20; t++) {
        __syncthreads();
        B[tid] = v0;
        B[256 + tid] = v1;
        if (tid < 32) B[512 + tid] = v2;
        __syncthreads();
        if (t < 19) {
            size_t ts = (size_t)(t + 1) * 65536;
            v0 = v0ok ? sp1w[ts + base0] : 0ull;
            v1 = v1ok ? sp1w[ts + base1] : 0ull;
            v2 = v2ok ? sp1w[ts + base2] : 0ull;
        }

        float acc[8];
        #pragma unroll
        for (int i = 0; i < 8; i++) acc[i] = 0.0f;
        const unsigned long long* Bp = &B[2 * r];
        #pragma unroll 4
        for (int ic = 0; ic < 32; ic++) {
            #pragma unroll
            for (int kh = 0; kh < 3; kh++) {
                unsigned long long m = Bp[ic * 17 + kh];
                uint32_t bits = (sshift >= 0) ? (uint32_t)(m >> sshift)
                                              : (((uint32_t)m) << 1);
                float f0 = (float)(bits & 1u);
                float f1 = (float)((bits >> 1) & 1u);
                float f2 = (float)((bits >> 2) & 1u);
                float f3 = (float)((bits >> 3) & 1u);
                float f4 = (float)((bits >> 4) & 1u);
                const float* wb = &wl[(ic * 9 + kh * 3) * 32 + oc0];
                float4 wk0 = *(const float4*)(wb);
                float4 wk1 = *(const float4*)(wb + 32);
                float4 wk2 = *(const float4*)(wb + 64);
                acc[0] += wk0.x * f0;  acc[1] += wk0.x * f2;
                acc[2] += wk0.y * f0;  acc[3] += wk0.y * f2;
                acc[4] += wk0.z * f0;  acc[5] += wk0.z * f2;
                acc[6] += wk0.w * f0;  acc[7] += wk0.w * f2;
                acc[0] += wk1.x * f1;  acc[1] += wk1.x * f3;
                acc[2] += wk1.y * f1;  acc[3] += wk1.y * f3;
                acc[4] += wk1.z * f1;  acc[5] += wk1.z * f3;
                acc[6] += wk1.w * f1;  acc[7] += wk1.w * f3;
                acc[0] += wk2.x * f2;  acc[1] += wk2.x * f4;
                acc[2] += wk2.y * f2;  acc[3] += wk2.y * f4;
                acc[4] += wk2.z * f2;  acc[5] += wk2.z * f4;
                acc[6] += wk2.w * f2;  acc[7] += wk2.w * f4;
            }
        }

        uint32_t p = 0;
        #pragma unroll
        for (int k = 0; k < 4; k++) {
            float bkk = ((const float*)&bias)[k];
            uint32_t v = 0;
            #pragma unroll
            for (int w = 0; w < 2; w++) {
                float conv = acc[k * 2 + w] + bkk;
                float pp = pot[k * 2 + w];
                float u = (pp > TH) ? conv : (pp * DECAY + conv);
                pot[k * 2 + w] = u;
                if (u > TH) v |= 1u << (owl + w);
            }
            p |= v << (8 * k);
        }
        p |= __shfl_xor((int)p, 1);
        p |= __shfl_xor((int)p, 2);
        if (owp == 0) {
            #pragma unroll
            for (int k = 0; k < 4; k++)
                sp2[(((size_t)(t * 32 + b) * 32 + (oc0 + k)) * 32 + (oh0 + r)) * 4 + (ow0 >> 3)]
                    = (uint8_t)(p >> (8 * k));
        }
    }
}

// -------------------------------------------------------------------------
// Fallback fused k3 if ws is too small for S3.
// -------------------------------------------------------------------------
__global__ __launch_bounds__(256, 3)
void k3_fused(const uint8_t* __restrict__ sp2, const float* __restrict__ w3,
              const float* __restrict__ b3, float* __restrict__ out)
{
    __shared__ float wl[9216];
    __shared__ float P[8 * 9 * 18];

    const int tid  = threadIdx.x;
    const int b    = blockIdx.x >> 3;
    const int tile = blockIdx.x & 7;
    const int oh0  = (tile >> 1) << 2;
    const int ow0  = (tile & 1) << 3;

    for (int idx = tid; idx < 9216; idx += 256) {
        int oc = idx & 31, rest = idx >> 5;
        int ic = rest / 9, r9 = rest - ic * 9;
        wl[idx] = w3[(oc * 32 + ic) * 9 + r9];
    }

    const int ocg = tid >> 4, oc0 = ocg << 1;
    const int sl = tid & 15, r = sl >> 2, owp = sl & 3, owl = owp << 1;
    const float2 bias = *(const float2*)&b3[oc0];
    float pot[4];
    uint32_t om[4];
    #pragma unroll
    for (int i = 0; i < 4; i++) { pot[i] = 0.0f; om[i] = 0u; }

    for (int t = 0; t < 20; t++) {
        float acc[4];
        #pragma unroll
        for (int i = 0; i < 4; i++) acc[i] = 0.0f;
        for (int cc = 0; cc < 4; cc++) {
            __syncthreads();
            if (tid < 72) {
                int ic = tid / 9, ihl = tid - ic * 9;
                int ih = 2 * oh0 - 1 + ihl;
                uint32_t rowb = 0u;
                if (ih >= 0)
                    rowb = *(const uint32_t*)
                           &sp2[(((size_t)(t * 32 + b) * 32 + (cc * 8 + ic)) * 32 + ih) * 4];
                float* dst = &P[(ic * 9 + ihl) * 18];
                #pragma unroll
                for (int iwl = 0; iwl < 17; iwl++) {
                    int iw = 2 * ow0 - 1 + iwl;
                    int col = (iwl & 1) ? ((iwl - 1) >> 1) : (8 + (iwl >> 1));
                    dst[col] = (iw >= 0 && ((rowb >> iw) & 1u)) ? 1.0f : 0.0f;
                }
            }
            __syncthreads();
            #pragma unroll
            for (int ic = 0; ic < 8; ic++) {
                #pragma unroll
                for (int kh = 0; kh < 3; kh++) {
                    const float* row = &P[(ic * 9 + 2 * r + kh) * 18];
                    float eA = row[owl],     eB = row[owl + 1];
                    float oA = row[8 + owl], oB = row[9 + owl], oC = row[10 + owl];
                    const float* wb = &wl[((cc * 8 + ic) * 9 + kh * 3) * 32 + oc0];
                    float2 w0  = *(const float2*)(wb);
                    float2 w1v = *(const float2*)(wb + 32);
                    float2 w2v = *(const float2*)(wb + 64);
                    acc[0] += w0.x * oA;  acc[1] += w0.x * oB;
                    acc[2] += w0.y * oA;  acc[3] += w0.y * oB;
                    acc[0] += w1v.x * eA; acc[1] += w1v.x * eB;
                    acc[2] += w1v.y * eA; acc[3] += w1v.y * eB;
                    acc[0] += w2v.x * oB; acc[1] += w2v.x * oC;
                    acc[2] += w2v.y * oB; acc[3] += w2v.y * oC;
                }
            }
        }
        #pragma unroll
        for (int k = 0; k < 2; k++) {
            float bk = (k == 0) ? bias.x : bias.y;
            #pragma unroll
            for (int w = 0; w < 2; w++) {
                float conv = acc[k * 2 + w] + bk;
                float pp = pot[k * 2 + w];
                float u = (pp > TH) ? conv : (pp * DECAY + conv);
                pot[k * 2 + w] = u;
                if (u > TH) om[k * 2 + w] |= 1u << t;
            }
        }
    }

    #pragma unroll
    for (int k = 0; k < 2; k++) {
        #pragma unroll
        for (int w = 0; w < 2; w++) {
            int oc = oc0 + k;
            int oh = oh0 + r, ow = ow0 + owl + w;
            int i = (oc << 8) + (oh << 4) + ow;
            float* dst = &out[((size_t)b * 8192 + i) * 20];
            uint32_t m = om[k * 2 + w];
            #pragma unroll
            for (int qq = 0; qq < 5; qq++) {
                float4 v;
                v.x = ((m >> (qq * 4 + 0)) & 1u) ? 1.0f : 0.0f;
                v.y = ((m >> (qq * 4 + 1)) & 1u) ? 1.0f : 0.0f;
                v.z = ((m >> (qq * 4 + 2)) & 1u) ? 1.0f : 0.0f;
                v.w = ((m >> (qq * 4 + 3)) & 1u) ? 1.0f : 0.0f;
                *(float4*)&dst[qq * 4] = v;
            }
        }
    }
}

extern "C" void kernel_launch(void* const* d_in, const int* in_sizes, int n_in,
                              void* d_out, int out_size, void* d_ws, size_t ws_size,
                              hipStream_t stream)
{
    (void)in_sizes; (void)n_in; (void)out_size;
    const float* in = (const float*)d_in[0];
    const float* w1 = (const float*)d_in[1];
    const float* b1 = (const float*)d_in[2];
    const float* w2 = (const float*)d_in[3];
    const float* b2 = (const float*)d_in[4];
    const float* w3 = (const float*)d_in[5];
    const float* b3 = (const float*)d_in[6];

    const size_t SP1_BYTES = (size_t)20 * 32 * 32 * 64 * 8;    // 10,485,760
    const size_t SP2_BYTES = (size_t)20 * 32 * 32 * 32 * 4;    //  2,621,440
    const size_t S2_BYTES  = (size_t)20 * 32 * 32 * 1024 * 4;  // 83,886,080
    const size_t S3_BYTES  = (size_t)20 * 32 * 32 * 256 * 4;   // 20,971,520
    const size_t WT_BYTES  = (size_t)9216 * 4;                 //     36,864

    uint8_t* base = (uint8_t*)d_ws;
    const bool full = ws_size >= SP1_BYTES + SP2_BYTES + S2_BYTES;        // 97.0 MB
    const bool mid  = ws_size >= S3_BYTES + SP2_BYTES + WT_BYTES;         // 23.7 MB

    if (full) {
        uint8_t* sp1 = base;
        uint8_t* sp2 = base + SP1_BYTES;
        float*   S2  = (float*)(base + SP1_BYTES + SP2_BYTES);
        float*   S3  = (float*)(base + SP1_BYTES + SP2_BYTES);    // overlays dead S2 head
        float*   w2t = (float*)sp2;                               // sp2 region dead until k2b
        float*   w3t = (float*)(base + SP1_BYTES + SP2_BYTES + S3_BYTES); // dead S2 tail
        k1_conv<<<32 * 64, 256, 0, stream>>>(in, w1, b1, sp1);
        wt_prep<<<36, 256, 0, stream>>>(w2, w2t);
        k2a_conv<<<20 * 32 * 2, 256, 0, stream>>>(sp1, w2t, S2);
        k2b_rec<<<32 * 32 * 4, 256, 0, stream>>>(S2, b2, sp2);    // overwrites w2t (dead)
        wt_prep<<<36, 256, 0, stream>>>(w3, w3t);                 // after k2b: S2 dead
        k3a_conv<<<20 * 32, 256, 0, stream>>>(sp2, w3t, S3);
        k3b_rec<<<32 * 32, 256, 0, stream>>>(S3, b3, (float*)d_out);
    } else if (mid) {
        uint8_t* sp1 = base;                  // dead before k3a writes S3
        float*   S3  = (float*)base;
        uint8_t* sp2 = base + S3_BYTES;
        float*   w3t = (float*)(base + S3_BYTES + SP2_BYTES);
        k1_conv<<<32 * 64, 256, 0, stream>>>(in, w1, b1, sp1);
        k2_conv<<<32 * 16, 256, 0, stream>>>(sp1, w2, b2, sp2);
        wt_prep<<<36, 256, 0, stream>>>(w3, w3t);
        k3a_conv<<<20 * 32, 256, 0, stream>>>(sp2, w3t, S3);
        k3b_rec<<<32 * 32, 256, 0, stream>>>(S3, b3, (float*)d_out);
    } else {
        uint8_t* sp1 = base;
        uint8_t* sp2 = base + SP1_BYTES;
        k1_conv<<<32 * 64, 256, 0, stream>>>(in, w1, b1, sp1);
        k2_conv<<<32 * 16, 256, 0, stream>>>(sp1, w2, b2, sp2);
        k3_fused<<<32 * 8, 256, 0, stream>>>(sp2, w3, b3, (float*)d_out);
    }
}

// Round 7
// 428.401 us; speedup vs baseline: 3.3430x; 1.1323x over previous
//
#include <hip/hip_runtime.h>
#include <cstdint>

// SpikeModel: 3-layer stride-2 3x3 spiking CNN, T=20, bs=32.
// k1v2: conv1 fused over t. Block=512 (8 waves) = one (b,out-row); wave =
//       4 oc x 64 cols (lane=col). LDS 63.4KB E/O planes; conflict-free
//       b32 tap reads; SGPR weights (w1t) via pk_fma; ballot -> u64 row.
// k2a:  conv2 SUMS, wave-uniform ocg, SGPR weights, bits-only LDS. (r6)
// k2b:  elementwise membrane recurrence, ballot -> sp2 bits. (r4)
// k3a:  conv3 sums, wave-uniform structure. (r6)
// k3b:  recurrence + t-inner output. (r2)
// Fallback paths (mid/low ws) keep the r3 fused k1/k2/k3 kernels.
// EXACTNESS CONTRACT: every accumulator chain is fused-FMA in (ic asc,
// kh asc, kw asc) order, bias last — bit-identical to rounds 1-6 (absmax
// 0.0 six times). pk halves are independent chains. Do not reorder.

#define DECAY 0.2f
#define TH 0.5f

typedef float v2f __attribute__((ext_vector_type(2)));

// acc = w*f + acc, packed: w wave-uniform (SGPR pair), f = {f,f} VGPR pair.
static __device__ __forceinline__ v2f pk_fma_sv(v2f w, v2f f, v2f acc) {
    asm("v_pk_fma_f32 %0, %1, %2, %0" : "+v"(acc) : "s"(w), "v"(f));
    return acc;
}

// -------------------------------------------------------------------------
// Weight transposes.
// wt_prep (32ic):  wt[((ocg*32+ic)*9+r9)*8+ocl] = w[((ocg*8+ocl)*32+ic)*9+r9]
// wt_prep1 (2ic):  wt[((wv*2+ic)*9+r9)*4+ocl]  = w[((wv*4+ocl)*2+ic)*9+r9]
// -------------------------------------------------------------------------
__global__ __launch_bounds__(256, 4)
void wt_prep(const float* __restrict__ w, float* __restrict__ wt)
{
    int idx = blockIdx.x * 256 + threadIdx.x;
    if (idx < 9216) {
        int ocl = idx & 7;
        int r9  = (idx >> 3) % 9;
        int icg = idx / 72;
        int ic  = icg & 31;
        int ocg = icg >> 5;
        wt[idx] = w[((ocg * 8 + ocl) * 32 + ic) * 9 + r9];
    }
}

__global__ __launch_bounds__(256, 4)
void wt_prep1(const float* __restrict__ w, float* __restrict__ wt)
{
    int idx = blockIdx.x * 256 + threadIdx.x;
    if (idx < 576) {
        int ocl = idx & 3;
        int r9  = (idx >> 2) % 9;
        int icg = idx / 36;
        int ic  = icg & 1;
        int wv  = icg >> 1;
        wt[idx] = w[((wv * 4 + ocl) * 2 + ic) * 9 + r9];
    }
}

// -------------------------------------------------------------------------
// Kernel 1 v2: conv1 (IC=2, 128x128 -> OC=32, 64x64), grid 32*64, block 512.
// P[t][(ic*3+kh)*132]: E (even iw, idx=iw/2) at +0..63; O (odd iw incl -1,
// idx=(iw+1)/2) at +64..128. Out col c taps: o0=O[c]@64+c, e=E[c]@c,
// o1=O[c+1]@65+c.
// -------------------------------------------------------------------------
__global__ __launch_bounds__(512, 4)
void k1_conv_v2(const float* __restrict__ in, const float* __restrict__ w1t,
                const float* __restrict__ b1, uint8_t* __restrict__ sp1)
{
    __shared__ float P[20 * 792];   // 63,360 B

    const int tid = threadIdx.x;
    const int b   = blockIdx.x >> 6;
    const int row = blockIdx.x & 63;

    // stage 3 rows x 129 cols x 2 ic x 20 t; q-inner => lane-consecutive 16B
    for (int idx = tid; idx < 3870; idx += 512) {
        int q = idx % 5, px = idx / 5;
        int iwl = px % 129, rest = px / 129;
        int ihl = rest % 3, ic = rest / 3;
        int ih = 2 * row - 1 + ihl;
        int iw = iwl - 1;
        float4 v = make_float4(0.f, 0.f, 0.f, 0.f);
        if (ih >= 0 && iw >= 0)
            v = *(const float4*)&in[(((size_t)(b * 2 + ic) * 128 + ih) * 128 + iw) * 20 + q * 4];
        int col = (iwl & 1) ? ((iwl - 1) >> 1) : (64 + (iwl >> 1));
        float* dst = &P[(ic * 3 + ihl) * 132 + col];
        int t0 = q * 4;
        dst[(t0 + 0) * 792] = v.x;
        dst[(t0 + 1) * 792] = v.y;
        dst[(t0 + 2) * 792] = v.z;
        dst[(t0 + 3) * 792] = v.w;
    }

    const int wv = __builtin_amdgcn_readfirstlane(tid >> 6);   // wave id 0..7
    const int c  = tid & 63;                                   // out col = lane
    const float* wp = w1t + wv * 72;                           // [ic*9+r9][4oc]

    const float bb0 = b1[wv * 4 + 0];
    const float bb1 = b1[wv * 4 + 1];
    const float bb2 = b1[wv * 4 + 2];
    const float bb3 = b1[wv * 4 + 3];

    v2f pot01 = (v2f){0.0f, 0.0f};
    v2f pot23 = (v2f){0.0f, 0.0f};
    unsigned long long* sp1w = (unsigned long long*)sp1;

    __syncthreads();

    for (int t = 0; t < 20; t++) {
        v2f a01 = (v2f){0.0f, 0.0f};
        v2f a23 = (v2f){0.0f, 0.0f};
        const float* Pt = &P[t * 792];
        #pragma unroll
        for (int ic = 0; ic < 2; ic++) {
            #pragma unroll
            for (int kh = 0; kh < 3; kh++) {
                const float* rowp = Pt + (ic * 3 + kh) * 132;
                float e  = rowp[c];
                float o0 = rowp[64 + c];
                float o1 = rowp[65 + c];
                const float* wb = wp + (ic * 9 + kh * 3) * 4;
                v2f f;
                f = (v2f){o0, o0};                       // kw=0
                a01 = pk_fma_sv(*(const v2f*)(wb + 0), f, a01);
                a23 = pk_fma_sv(*(const v2f*)(wb + 2), f, a23);
                f = (v2f){e, e};                         // kw=1
                a01 = pk_fma_sv(*(const v2f*)(wb + 4), f, a01);
                a23 = pk_fma_sv(*(const v2f*)(wb + 6), f, a23);
                f = (v2f){o1, o1};                       // kw=2
                a01 = pk_fma_sv(*(const v2f*)(wb + 8), f, a01);
                a23 = pk_fma_sv(*(const v2f*)(wb + 10), f, a23);
            }
        }
        float u0, u1, u2, u3;
        { float conv = a01.x + bb0; float pp = pot01.x;
          u0 = (pp > TH) ? conv : (pp * DECAY + conv); pot01.x = u0; }
        { float conv = a01.y + bb1; float pp = pot01.y;
          u1 = (pp > TH) ? conv : (pp * DECAY + conv); pot01.y = u1; }
        { float conv = a23.x + bb2; float pp = pot23.x;
          u2 = (pp > TH) ? conv : (pp * DECAY + conv); pot23.x = u2; }
        { float conv = a23.y + bb3; float pp = pot23.y;
          u3 = (pp > TH) ? conv : (pp * DECAY + conv); pot23.y = u3; }
        unsigned long long m0 = __ballot(u0 > TH);
        unsigned long long m1 = __ballot(u1 > TH);
        unsigned long long m2 = __ballot(u2 > TH);
        unsigned long long m3 = __ballot(u3 > TH);
        size_t wbase = ((size_t)(t * 32 + b) * 32 + wv * 4) * 64 + row;
        if (c == 0) sp1w[wbase]       = m0;
        if (c == 1) sp1w[wbase + 64]  = m1;
        if (c == 2) sp1w[wbase + 128] = m2;
        if (c == 3) sp1w[wbase + 192] = m3;
    }
}

// -------------------------------------------------------------------------
// Kernel 1 (r3 version, used by mid/low ws fallback paths).
// -------------------------------------------------------------------------
__global__ __launch_bounds__(256, 2)
void k1_conv(const float* __restrict__ in, const float* __restrict__ w1,
             const float* __restrict__ b1, uint8_t* __restrict__ sp1)
{
    __shared__ float P[20 * 816];

    const int tid = threadIdx.x;
    const int b   = blockIdx.x >> 6;
    const int row = blockIdx.x & 63;

    for (int idx = tid; idx < 3870; idx += 256) {
        int q = idx % 5, px = idx / 5;
        int iwl = px % 129, rest = px / 129;
        int ihl = rest % 3, ic = rest / 3;
        int ih = 2 * row - 1 + ihl;
        int iw = iwl - 1;
        float4 v = make_float4(0.f, 0.f, 0.f, 0.f);
        if (ih >= 0 && iw >= 0)
            v = *(const float4*)&in[(((size_t)(b * 2 + ic) * 128 + ih) * 128 + iw) * 20 + q * 4];
        int col = (iwl & 1) ? ((iwl - 1) >> 1) : (68 + (iwl >> 1));
        float* dst = &P[(ic * 3 + ihl) * 136 + col];
        int t0 = q * 4;
        dst[(t0 + 0) * 816] = v.x;
        dst[(t0 + 1) * 816] = v.y;
        dst[(t0 + 2) * 816] = v.z;
        dst[(t0 + 3) * 816] = v.w;
    }

    const int oc = tid >> 3;
    const int tw = tid & 7;

    float w[18];
    #pragma unroll
    for (int ic = 0; ic < 2; ic++)
        #pragma unroll
        for (int k9 = 0; k9 < 9; k9++)
            w[ic * 9 + k9] = w1[(oc * 2 + ic) * 9 + k9];
    const float bk = b1[oc];

    float pot[8];
    #pragma unroll
    for (int i = 0; i < 8; i++) pot[i] = 0.0f;

    __syncthreads();

    for (int t = 0; t < 20; t++) {
        float acc[8];
        #pragma unroll
        for (int i = 0; i < 8; i++) acc[i] = 0.0f;
        const float* Pt = &P[t * 816];
        #pragma unroll
        for (int ic = 0; ic < 2; ic++) {
            #pragma unroll
            for (int kh = 0; kh < 3; kh++) {
                const float* rowp = Pt + (ic * 3 + kh) * 136;
                float4 e0 = *(const float4*)&rowp[8 * tw];
                float4 e1 = *(const float4*)&rowp[8 * tw + 4];
                float4 o0 = *(const float4*)&rowp[68 + 8 * tw];
                float4 o1 = *(const float4*)&rowp[68 + 8 * tw + 4];
                float  o8 = rowp[68 + 8 * tw + 8];
                float wk0 = w[ic * 9 + kh * 3 + 0];
                float wk1 = w[ic * 9 + kh * 3 + 1];
                float wk2 = w[ic * 9 + kh * 3 + 2];
                acc[0] += wk0 * o0.x; acc[1] += wk0 * o0.y;
                acc[2] += wk0 * o0.z; acc[3] += wk0 * o0.w;
                acc[4] += wk0 * o1.x; acc[5] += wk0 * o1.y;
                acc[6] += wk0 * o1.z; acc[7] += wk0 * o1.w;
                acc[0] += wk1 * e0.x; acc[1] += wk1 * e0.y;
                acc[2] += wk1 * e0.z; acc[3] += wk1 * e0.w;
                acc[4] += wk1 * e1.x; acc[5] += wk1 * e1.y;
                acc[6] += wk1 * e1.z; acc[7] += wk1 * e1.w;
                acc[0] += wk2 * o0.y; acc[1] += wk2 * o0.z;
                acc[2] += wk2 * o0.w; acc[3] += wk2 * o1.x;
                acc[4] += wk2 * o1.y; acc[5] += wk2 * o1.z;
                acc[6] += wk2 * o1.w; acc[7] += wk2 * o8;
            }
        }
        uint32_t v = 0;
        #pragma unroll
        for (int j = 0; j < 8; j++) {
            float conv = acc[j] + bk;
            float pp = pot[j];
            float u = (pp > TH) ? conv : (pp * DECAY + conv);
            pot[j] = u;
            if (u > TH) v |= 1u << j;
        }
        sp1[(((size_t)(t * 32 + b) * 32 + oc) * 64 + row) * 8 + tw] = (uint8_t)v;
    }
}

// -------------------------------------------------------------------------
// Kernel 2a: conv2 sums (IC=32, 64x64 -> OC=32, 32x32). (r6)
// -------------------------------------------------------------------------
__global__ __launch_bounds__(256, 4)
void k2a_conv(const uint8_t* __restrict__ sp1, const float* __restrict__ w2t,
              float* __restrict__ S2)
{
    __shared__ unsigned long long B[1056];

    const int tid  = threadIdx.x;
    const int bid  = blockIdx.x;
    const int t    = bid >> 6;
    const int rem  = bid & 63;
    const int b    = rem >> 1;
    const int band = rem & 1;
    const int oh0  = band << 4;

    const unsigned long long* sp1w = (const unsigned long long*)sp1;
    for (int idx = tid; idx < 1056; idx += 256) {
        int ic = idx / 33, ihl = idx - ic * 33;
        int ih = 2 * oh0 - 1 + ihl;
        B[idx] = (ih >= 0) ? sp1w[((size_t)(t * 32 + b) * 32 + ic) * 64 + ih] : 0ull;
    }
    __syncthreads();

    const int ocgu = __builtin_amdgcn_readfirstlane(tid >> 6);
    const int lane = tid & 63;
    const int r    = lane >> 2;
    const int owq  = lane & 3;
    const float* wt = w2t + ocgu * 2304;

    v2f acc[4][8];
    #pragma unroll
    for (int k = 0; k < 4; k++)
        #pragma unroll
        for (int j = 0; j < 8; j++) acc[k][j] = (v2f){0.0f, 0.0f};

    #pragma unroll 2
    for (int ic = 0; ic < 32; ic++) {
        #pragma unroll
        for (int kh = 0; kh < 3; kh++) {
            unsigned long long m = B[ic * 33 + 2 * r + kh];
            uint32_t bits = owq ? (uint32_t)(m >> (16 * owq - 1))
                                : (((uint32_t)m) << 1);
            v2f fp[17];
            #pragma unroll
            for (int i = 0; i < 17; i++) {
                float fv = (float)((bits >> i) & 1u);
                fp[i] = (v2f){fv, fv};
            }
            const float* wpp = wt + (ic * 9 + kh * 3) * 8;
            #pragma unroll
            for (int kw = 0; kw < 3; kw++) {
                #pragma unroll
                for (int ocp = 0; ocp < 4; ocp++) {
                    v2f wv = *(const v2f*)(wpp + kw * 8 + 2 * ocp);
                    #pragma unroll
                    for (int j = 0; j < 8; j++)
                        acc[ocp][j] = pk_fma_sv(wv, fp[2 * j + kw], acc[ocp][j]);
                }
            }
        }
    }

    #pragma unroll
    for (int ocp = 0; ocp < 4; ocp++) {
        const int oc = ocgu * 8 + 2 * ocp;
        size_t base = ((size_t)(t * 32 + b) * 32 + oc) * 1024 + (oh0 + r) * 32 + owq * 8;
        float4 x0 = make_float4(acc[ocp][0].x, acc[ocp][1].x, acc[ocp][2].x, acc[ocp][3].x);
        float4 x1 = make_float4(acc[ocp][4].x, acc[ocp][5].x, acc[ocp][6].x, acc[ocp][7].x);
        float4 y0 = make_float4(acc[ocp][0].y, acc[ocp][1].y, acc[ocp][2].y, acc[ocp][3].y);
        float4 y1 = make_float4(acc[ocp][4].y, acc[ocp][5].y, acc[ocp][6].y, acc[ocp][7].y);
        *(float4*)&S2[base] = x0;
        *(float4*)&S2[base + 4] = x1;
        *(float4*)&S2[base + 1024] = y0;
        *(float4*)&S2[base + 1028] = y1;
    }
}

// -------------------------------------------------------------------------
// Kernel 2b: membrane recurrence for layer 2, grid 32*32*4, block 256.
// -------------------------------------------------------------------------
__global__ __launch_bounds__(256, 4)
void k2b_rec(const float* __restrict__ S2, const float* __restrict__ b2,
             uint8_t* __restrict__ sp2)
{
    const int bid = blockIdx.x;
    const int b   = bid >> 7;
    const int rem = bid & 127;
    const int oc  = rem >> 2;
    const int q   = rem & 3;
    const int tid = threadIdx.x;
    const int px  = q * 256 + tid;
    const float bk = b2[oc];
    uint32_t* sp2w = (uint32_t*)sp2;

    float sv[20];
    #pragma unroll
    for (int t = 0; t < 20; t++)
        sv[t] = S2[((size_t)(t * 32 + b) * 32 + oc) * 1024 + px];

    const int lane = tid & 63;
    float p = 0.0f;
    #pragma unroll
    for (int t = 0; t < 20; t++) {
        float conv = sv[t] + bk;
        float u = (p > TH) ? conv : (p * DECAY + conv);
        p = u;
        unsigned long long mk = __ballot(u > TH);
        if (lane == 0)
            sp2w[((size_t)(t * 32 + b) * 32 + oc) * 32 + (px >> 5)] = (uint32_t)mk;
        if (lane == 32)
            sp2w[((size_t)(t * 32 + b) * 32 + oc) * 32 + (px >> 5)] = (uint32_t)(mk >> 32);
    }
}

// -------------------------------------------------------------------------
// Kernel 3a: conv3 sums (IC=32, 32x32 -> OC=32, 16x16), grid 20*32. (r6)
// -------------------------------------------------------------------------
__global__ __launch_bounds__(256, 4)
void k3a_conv(const uint8_t* __restrict__ sp2, const float* __restrict__ w3t,
              float* __restrict__ S3)
{
    __shared__ uint32_t Bs[1056];

    const int bid = blockIdx.x;
    const int t   = bid >> 5;
    const int b   = bid & 31;
    const int tid = threadIdx.x;
    const uint32_t* sp2w = (const uint32_t*)sp2;

    for (int idx = tid; idx < 1056; idx += 256) {
        int ic = idx / 33, ihl = idx - ic * 33;
        int ih = ihl - 1;
        Bs[idx] = (ih >= 0) ? sp2w[((size_t)(t * 32 + b) * 32 + ic) * 32 + ih] : 0u;
    }
    __syncthreads();

    const int ocgu = __builtin_amdgcn_readfirstlane(tid >> 6);
    const int lane = tid & 63;
    const int r    = lane >> 2;
    const int owq  = lane & 3;
    const float* wt = w3t + ocgu * 2304;

    v2f acc[4][4];
    #pragma unroll
    for (int k = 0; k < 4; k++)
        #pragma unroll
        for (int j = 0; j < 4; j++) acc[k][j] = (v2f){0.0f, 0.0f};

    #pragma unroll 2
    for (int ic = 0; ic < 32; ic++) {
        #pragma unroll
        for (int kh = 0; kh < 3; kh++) {
            uint32_t m = Bs[ic * 33 + 2 * r + kh];
            uint32_t bits = owq ? (m >> (8 * owq - 1)) : (m << 1);
            v2f fp[9];
            #pragma unroll
            for (int i = 0; i < 9; i++) {
                float fv = (float)((bits >> i) & 1u);
                fp[i] = (v2f){fv, fv};
            }
            const float* wpp = wt + (ic * 9 + kh * 3) * 8;
            #pragma unroll
            for (int kw = 0; kw < 3; kw++) {
                #pragma unroll
                for (int ocp = 0; ocp < 4; ocp++) {
                    v2f wv = *(const v2f*)(wpp + kw * 8 + 2 * ocp);
                    #pragma unroll
                    for (int j = 0; j < 4; j++)
                        acc[ocp][j] = pk_fma_sv(wv, fp[2 * j + kw], acc[ocp][j]);
                }
            }
        }
    }

    #pragma unroll
    for (int ocp = 0; ocp < 4; ocp++) {
        const int oc = ocgu * 8 + 2 * ocp;
        size_t base = ((size_t)(t * 32 + b) * 32 + oc) * 256 + r * 16 + owq * 4;
        float4 x0 = make_float4(acc[ocp][0].x, acc[ocp][1].x, acc[ocp][2].x, acc[ocp][3].x);
        float4 y0 = make_float4(acc[ocp][0].y, acc[ocp][1].y, acc[ocp][2].y, acc[ocp][3].y);
        *(float4*)&S3[base] = x0;
        *(float4*)&S3[base + 256] = y0;
    }
}

// -------------------------------------------------------------------------
// Kernel 3 phase B: membrane recurrence + t-inner output, grid 32*32.
// -------------------------------------------------------------------------
__global__ __launch_bounds__(256, 4)
void k3b_rec(const float* __restrict__ S3, const float* __restrict__ b3,
             float* __restrict__ out)
{
    const int b  = blockIdx.x >> 5;
    const int oc = blockIdx.x & 31;
    const int tid = threadIdx.x;
    const float bk = b3[oc];

    float p = 0.0f;
    uint32_t om = 0u;
    for (int t = 0; t < 20; t++) {
        float s = S3[((size_t)(t * 32 + b) * 32 + oc) * 256 + tid];
        float conv = s + bk;
        float u = (p > TH) ? conv : (p * DECAY + conv);
        p = u;
        if (u > TH) om |= 1u << t;
    }
    float* dst = &out[((size_t)b * 8192 + (oc << 8) + tid) * 20];
    #pragma unroll
    for (int qq = 0; qq < 5; qq++) {
        float4 v;
        v.x = ((om >> (qq * 4 + 0)) & 1u) ? 1.0f : 0.0f;
        v.y = ((om >> (qq * 4 + 1)) & 1u) ? 1.0f : 0.0f;
        v.z = ((om >> (qq * 4 + 2)) & 1u) ? 1.0f : 0.0f;
        v.w = ((om >> (qq * 4 + 3)) & 1u) ? 1.0f : 0.0f;
        *(float4*)&dst[qq * 4] = v;
    }
}

// -------------------------------------------------------------------------
// Kernel 2 (FALLBACK, fused over t): round-3 version.
// -------------------------------------------------------------------------
__global__ __launch_bounds__(256, 2)
void k2_conv(const uint8_t* __restrict__ sp1, const float* __restrict__ w2,
             const float* __restrict__ b2, uint8_t* __restrict__ sp2)
{
    __shared__ float wl[9216];
    __shared__ unsigned long long B[544];

    const int tid  = threadIdx.x;
    const int b    = blockIdx.x >> 4;
    const int tile = blockIdx.x & 15;
    const int oh0  = (tile >> 2) << 3;
    const int ow0  = (tile & 3) << 3;

    for (int idx = tid; idx < 9216; idx += 256) {
        int oc = idx & 31, rest = idx >> 5;
        int ic = rest / 9, r9 = rest - ic * 9;
        wl[idx] = w2[(oc * 32 + ic) * 9 + r9];
    }

    const unsigned long long* sp1w = (const unsigned long long*)sp1;
    int w0i = tid, w1i = 256 + tid, w2i = 512 + tid;
    int ic0s = w0i / 17, ih0 = 2 * oh0 - 1 + (w0i - ic0s * 17);
    int ic1s = w1i / 17, ih1 = 2 * oh0 - 1 + (w1i - ic1s * 17);
    int ic2s = w2i / 17, ih2 = 2 * oh0 - 1 + (w2i - ic2s * 17);
    const size_t base0 = (size_t)(b * 32 + ic0s) * 64 + ih0;
    const size_t base1 = (size_t)(b * 32 + ic1s) * 64 + ih1;
    const size_t base2 = (size_t)(b * 32 + ic2s) * 64 + ih2;
    const bool v0ok = (ih0 >= 0), v1ok = (ih1 >= 0), v2ok = (tid < 32) && (ih2 >= 0);

    unsigned long long v0 = v0ok ? sp1w[base0] : 0ull;
    unsigned long long v1 = v1ok ? sp1w[base1] : 0ull;
    unsigned long long v2 = v2ok ? sp1w[base2] : 0ull;

    const int oc0 = (tid >> 5) << 2;
    const int sl  = tid & 31;
    const int r   = sl >> 2;
    const int owp = sl & 3, owl = owp << 1;
    const int sshift = 2 * (ow0 + owl) - 1;

    const float4 bias = *(const float4*)&b2[oc0];
    float pot[8];
    #pragma unroll
    for (int i = 0; i < 8; i++) pot[i] = 0.0f;

    for (int t = 0; t < 20; t++) {
        __syncthreads();
        B[tid] = v0;
        B[256 + tid] = v1;
        if (tid < 32) B[512 + tid] = v2;
        __syncthreads();
        if (t < 19) {
            size_t ts = (size_t)(t + 1) * 65536;
            v0 = v0ok ? sp1w[ts + base0] : 0ull;
            v1 = v1ok ? sp1w[ts + base1] : 0ull;
            v2 = v2ok ? sp1w[ts + base2] : 0ull;
        }

        float acc[8];
        #pragma unroll
        for (int i = 0; i < 8; i++) acc[i] = 0.0f;
        const unsigned long long* Bp = &B[2 * r];
        #pragma unroll 4
        for (int ic = 0; ic < 32; ic++) {
            #pragma unroll
            for (int kh = 0; kh < 3; kh++) {
                unsigned long long m = Bp[ic * 17 + kh];
                uint32_t bits = (sshift >= 0) ? (uint32_t)(m >> sshift)
                                              : (((uint32_t)m) << 1);
                float f0 = (float)(bits & 1u);
                float f1 = (float)((bits >> 1) & 1u);
                float f2 = (float)((bits >> 2) & 1u);
                float f3 = (float)((bits >> 3) & 1u);
                float f4 = (float)((bits >> 4) & 1u);
                const float* wb = &wl[(ic * 9 + kh * 3) * 32 + oc0];
                float4 wk0 = *(const float4*)(wb);
                float4 wk1 = *(const float4*)(wb + 32);
                float4 wk2 = *(const float4*)(wb + 64);
                acc[0] += wk0.x * f0;  acc[1] += wk0.x * f2;
                acc[2] += wk0.y * f0;  acc[3] += wk0.y * f2;
                acc[4] += wk0.z * f0;  acc[5] += wk0.z * f2;
                acc[6] += wk0.w * f0;  acc[7] += wk0.w * f2;
                acc[0] += wk1.x * f1;  acc[1] += wk1.x * f3;
                acc[2] += wk1.y * f1;  acc[3] += wk1.y * f3;
                acc[4] += wk1.z * f1;  acc[5] += wk1.z * f3;
                acc[6] += wk1.w * f1;  acc[7] += wk1.w * f3;
                acc[0] += wk2.x * f2;  acc[1] += wk2.x * f4;
                acc[2] += wk2.y * f2;  acc[3] += wk2.y * f4;
                acc[4] += wk2.z * f2;  acc[5] += wk2.z * f4;
                acc[6] += wk2.w * f2;  acc[7] += wk2.w * f4;
            }
        }

        uint32_t p = 0;
        #pragma unroll
        for (int k = 0; k < 4; k++) {
            float bkk = ((const float*)&bias)[k];
            uint32_t v = 0;
            #pragma unroll
            for (int w = 0; w < 2; w++) {
                float conv = acc[k * 2 + w] + bkk;
                float pp = pot[k * 2 + w];
                float u = (pp > TH) ? conv : (pp * DECAY + conv);
                pot[k * 2 + w] = u;
                if (u > TH) v |= 1u << (owl + w);
            }
            p |= v << (8 * k);
        }
        p |= __shfl_xor((int)p, 1);
        p |= __shfl_xor((int)p, 2);
        if (owp == 0) {
            #pragma unroll
            for (int k = 0; k < 4; k++)
                sp2[(((size_t)(t * 32 + b) * 32 + (oc0 + k)) * 32 + (oh0 + r)) * 4 + (ow0 >> 3)]
                    = (uint8_t)(p >> (8 * k));
        }
    }
}

// -------------------------------------------------------------------------
// Fallback fused k3 if ws is too small for S3.
// -------------------------------------------------------------------------
__global__ __launch_bounds__(256, 3)
void k3_fused(const uint8_t* __restrict__ sp2, const float* __restrict__ w3,
              const float* __restrict__ b3, float* __restrict__ out)
{
    __shared__ float wl[9216];
    __shared__ float P[8 * 9 * 18];

    const int tid  = threadIdx.x;
    const int b    = blockIdx.x >> 3;
    const int tile = blockIdx.x & 7;
    const int oh0  = (tile >> 1) << 2;
    const int ow0  = (tile & 1) << 3;

    for (int idx = tid; idx < 9216; idx += 256) {
        int oc = idx & 31, rest = idx >> 5;
        int ic = rest / 9, r9 = rest - ic * 9;
        wl[idx] = w3[(oc * 32 + ic) * 9 + r9];
    }

    const int ocg = tid >> 4, oc0 = ocg << 1;
    const int sl = tid & 15, r = sl >> 2, owp = sl & 3, owl = owp << 1;
    const float2 bias = *(const float2*)&b3[oc0];
    float pot[4];
    uint32_t om[4];
    #pragma unroll
    for (int i = 0; i < 4; i++) { pot[i] = 0.0f; om[i] = 0u; }

    for (int t = 0; t < 20; t++) {
        float acc[4];
        #pragma unroll
        for (int i = 0; i < 4; i++) acc[i] = 0.0f;
        for (int cc = 0; cc < 4; cc++) {
            __syncthreads();
            if (tid < 72) {
                int ic = tid / 9, ihl = tid - ic * 9;
                int ih = 2 * oh0 - 1 + ihl;
                uint32_t rowb = 0u;
                if (ih >= 0)
                    rowb = *(const uint32_t*)
                           &sp2[(((size_t)(t * 32 + b) * 32 + (cc * 8 + ic)) * 32 + ih) * 4];
                float* dst = &P[(ic * 9 + ihl) * 18];
                #pragma unroll
                for (int iwl = 0; iwl < 17; iwl++) {
                    int iw = 2 * ow0 - 1 + iwl;
                    int col = (iwl & 1) ? ((iwl - 1) >> 1) : (8 + (iwl >> 1));
                    dst[col] = (iw >= 0 && ((rowb >> iw) & 1u)) ? 1.0f : 0.0f;
                }
            }
            __syncthreads();
            #pragma unroll
            for (int ic = 0; ic < 8; ic++) {
                #pragma unroll
                for (int kh = 0; kh < 3; kh++) {
                    const float* row = &P[(ic * 9 + 2 * r + kh) * 18];
                    float eA = row[owl],     eB = row[owl + 1];
                    float oA = row[8 + owl], oB = row[9 + owl], oC = row[10 + owl];
                    const float* wb = &wl[((cc * 8 + ic) * 9 + kh * 3) * 32 + oc0];
                    float2 w0  = *(const float2*)(wb);
                    float2 w1v = *(const float2*)(wb + 32);
                    float2 w2v = *(const float2*)(wb + 64);
                    acc[0] += w0.x * oA;  acc[1] += w0.x * oB;
                    acc[2] += w0.y * oA;  acc[3] += w0.y * oB;
                    acc[0] += w1v.x * eA; acc[1] += w1v.x * eB;
                    acc[2] += w1v.y * eA; acc[3] += w1v.y * eB;
                    acc[0] += w2v.x * oB; acc[1] += w2v.x * oC;
                    acc[2] += w2v.y * oB; acc[3] += w2v.y * oC;
                }
            }
        }
        #pragma unroll
        for (int k = 0; k < 2; k++) {
            float bk = (k == 0) ? bias.x : bias.y;
            #pragma unroll
            for (int w = 0; w < 2; w++) {
                float conv = acc[k * 2 + w] + bk;
                float pp = pot[k * 2 + w];
                float u = (pp > TH) ? conv : (pp * DECAY + conv);
                pot[k * 2 + w] = u;
                if (u > TH) om[k * 2 + w] |= 1u << t;
            }
        }
    }

    #pragma unroll
    for (int k = 0; k < 2; k++) {
        #pragma unroll
        for (int w = 0; w < 2; w++) {
            int oc = oc0 + k;
            int oh = oh0 + r, ow = ow0 + owl + w;
            int i = (oc << 8) + (oh << 4) + ow;
            float* dst = &out[((size_t)b * 8192 + i) * 20];
            uint32_t m = om[k * 2 + w];
            #pragma unroll
            for (int qq = 0; qq < 5; qq++) {
                float4 v;
                v.x = ((m >> (qq * 4 + 0)) & 1u) ? 1.0f : 0.0f;
                v.y = ((m >> (qq * 4 + 1)) & 1u) ? 1.0f : 0.0f;
                v.z = ((m >> (qq * 4 + 2)) & 1u) ? 1.0f : 0.0f;
                v.w = ((m >> (qq * 4 + 3)) & 1u) ? 1.0f : 0.0f;
                *(float4*)&dst[qq * 4] = v;
            }
        }
    }
}

extern "C" void kernel_launch(void* const* d_in, const int* in_sizes, int n_in,
                              void* d_out, int out_size, void* d_ws, size_t ws_size,
                              hipStream_t stream)
{
    (void)in_sizes; (void)n_in; (void)out_size;
    const float* in = (const float*)d_in[0];
    const float* w1 = (const float*)d_in[1];
    const float* b1 = (const float*)d_in[2];
    const float* w2 = (const float*)d_in[3];
    const float* b2 = (const float*)d_in[4];
    const float* w3 = (const float*)d_in[5];
    const float* b3 = (const float*)d_in[6];

    const size_t SP1_BYTES = (size_t)20 * 32 * 32 * 64 * 8;    // 10,485,760
    const size_t SP2_BYTES = (size_t)20 * 32 * 32 * 32 * 4;    //  2,621,440
    const size_t S2_BYTES  = (size_t)20 * 32 * 32 * 1024 * 4;  // 83,886,080
    const size_t S3_BYTES  = (size_t)20 * 32 * 32 * 256 * 4;   // 20,971,520
    const size_t WT_BYTES  = (size_t)9216 * 4;                 //     36,864

    uint8_t* base = (uint8_t*)d_ws;
    const bool full = ws_size >= SP1_BYTES + SP2_BYTES + S2_BYTES;        // 97.0 MB
    const bool mid  = ws_size >= S3_BYTES + SP2_BYTES + WT_BYTES;         // 23.7 MB

    if (full) {
        uint8_t* sp1 = base;
        uint8_t* sp2 = base + SP1_BYTES;
        float*   S2  = (float*)(base + SP1_BYTES + SP2_BYTES);
        float*   S3  = (float*)(base + SP1_BYTES + SP2_BYTES);    // overlays dead S2 head
        float*   w2t = (float*)sp2;                               // sp2 region dead until k2b
        float*   w1t = (float*)(sp2 + 65536);                     // same region, disjoint
        float*   w3t = (float*)(base + SP1_BYTES + SP2_BYTES + S3_BYTES); // dead S2 tail
        wt_prep1<<<3, 256, 0, stream>>>(w1, w1t);
        wt_prep<<<36, 256, 0, stream>>>(w2, w2t);
        k1_conv_v2<<<32 * 64, 512, 0, stream>>>(in, w1t, b1, sp1);
        k2a_conv<<<20 * 32 * 2, 256, 0, stream>>>(sp1, w2t, S2);
        k2b_rec<<<32 * 32 * 4, 256, 0, stream>>>(S2, b2, sp2);    // kills w1t/w2t (dead)
        wt_prep<<<36, 256, 0, stream>>>(w3, w3t);                 // after k2b: S2 dead
        k3a_conv<<<20 * 32, 256, 0, stream>>>(sp2, w3t, S3);
        k3b_rec<<<32 * 32, 256, 0, stream>>>(S3, b3, (float*)d_out);
    } else if (mid) {
        uint8_t* sp1 = base;                  // dead before k3a writes S3
        float*   S3  = (float*)base;
        uint8_t* sp2 = base + S3_BYTES;
        float*   w3t = (float*)(base + S3_BYTES + SP2_BYTES);
        k1_conv<<<32 * 64, 256, 0, stream>>>(in, w1, b1, sp1);
        k2_conv<<<32 * 16, 256, 0, stream>>>(sp1, w2, b2, sp2);
        wt_prep<<<36, 256, 0, stream>>>(w3, w3t);
        k3a_conv<<<20 * 32, 256, 0, stream>>>(sp2, w3t, S3);
        k3b_rec<<<32 * 32, 256, 0, stream>>>(S3, b3, (float*)d_out);
    } else {
        uint8_t* sp1 = base;
        uint8_t* sp2 = base + SP1_BYTES;
        k1_conv<<<32 * 64, 256, 0, stream>>>(in, w1, b1, sp1);
        k2_conv<<<32 * 16, 256, 0, stream>>>(sp1, w2, b2, sp2);
        k3_fused<<<32 * 8, 256, 0, stream>>>(sp2, w3, b3, (float*)d_out);
    }
}